// Round 6
// baseline (409.237 us; speedup 1.0000x reference)
//
#include <hip/hip_runtime.h>
#include <hip/hip_bf16.h>

// ---------------------------------------------------------------------------
// DecoderBlock: proj -> banded MHA -> LN+residual -> 3x conv1d(softplus) -> LN
// S=2048, L=5S=10240, DIM=512, HEADS=4, hd=128, KDIM=136 (pad->192), EXT=64
// GEMMs: WAVE-AUTONOMOUS 64x32 tiles, private double-buffered LDS per wave,
// ZERO barriers in the K-loop (self-paced s_waitcnt vmcnt(6) pipelines).
// Attention: banded one-shot MFMA flash (window <= 30 per 16-query tile).
// ---------------------------------------------------------------------------

#define S_LEN   2048
#define S_PAD   32       // zero pad rows on k_b/v_b for window overrun
#define L_LEN   10240
#define DIM     512
#define KDIM    136
#define KDIM_P  192      // padded to multiple of 32 (and 64)
#define NPOS    8
#define HEADS   4
#define HDIM    128
#define NLAYERS 3
#define CONV_K  1536

typedef __attribute__((ext_vector_type(8))) short bf16x8;
typedef __attribute__((ext_vector_type(4))) float f32x4;

__device__ __forceinline__ float softplus_f(float x) {
    return x > 20.0f ? x : log1pf(__expf(x));
}

__device__ __forceinline__ void gload_lds16(const __hip_bfloat16* g,
                                            __hip_bfloat16* l) {
    __builtin_amdgcn_global_load_lds(
        (const __attribute__((address_space(1))) void*)g,
        (__attribute__((address_space(3))) void*)l, 16, 0, 0);
}

// ---------------------------------------------------------------------------
// GEMM: C[m,n] = act( sum_k A[m*lda+k] * W[n*ldw+k] + bias[n] )
// Block = 128(m) x 64(n) = 4 waves in 2x2; each wave owns a 64x32 tile with
// PRIVATE double-buffered LDS (A 2x4KB, B 2x2KB). No __syncthreads/s_barrier
// in the K-loop: each wave prefetches its own tile k+1 (6 DMAs), waits
// vmcnt(6) for tile k, reads 6 frags, does 8 MFMAs. lgkmcnt(0) guards the
// WAR on the buffer being overwritten. Requires M%128==0, N%64==0, K%32==0.
// ---------------------------------------------------------------------------
template<bool SOFTPLUS, bool OUT_BF16>
__global__ __launch_bounds__(256) void gemm_wp(
    const __hip_bfloat16* __restrict__ A, int lda,
    const __hip_bfloat16* __restrict__ W, int ldw,
    const float* __restrict__ bias,
    __hip_bfloat16* __restrict__ Cb, float* __restrict__ Cf, int ldc,
    int K)
{
    __shared__ __hip_bfloat16 As[4 * 2 * 64 * 32];   // 32 KB: [wave][buf][64][32]
    __shared__ __hip_bfloat16 Bs[4 * 2 * 32 * 32];   // 16 KB: [wave][buf][32][32]

    const int t = threadIdx.x;
    const int w = t >> 6;
    const int lane = t & 63;
    const int r16 = lane & 15;
    const int quad = lane >> 4;

    const int m0 = blockIdx.x * 128 + (w >> 1) * 64;   // wave's m base
    const int n0 = blockIdx.y * 64 + (w & 1) * 32;     // wave's n base

    // staging: issue i covers 16 rows; lane -> row = lane>>2, col8 = lane&3
    const int srow = lane >> 2;
    const int scol = (lane & 3) * 8;
    const __hip_bfloat16* Ag0 = A + (size_t)(m0 + srow) * lda + scol;
    const __hip_bfloat16* Ag1 = A + (size_t)(m0 + 16 + srow) * lda + scol;
    const __hip_bfloat16* Ag2 = A + (size_t)(m0 + 32 + srow) * lda + scol;
    const __hip_bfloat16* Ag3 = A + (size_t)(m0 + 48 + srow) * lda + scol;
    const __hip_bfloat16* Wg0 = W + (size_t)(n0 + srow) * ldw + scol;
    const __hip_bfloat16* Wg1 = W + (size_t)(n0 + 16 + srow) * ldw + scol;
    __hip_bfloat16* lA = &As[(size_t)w * 4096];   // + buf*2048 later... (buf stride 2048 elems = 4KB)
    __hip_bfloat16* lB = &Bs[(size_t)w * 2048];   // + buf*1024

    f32x4 acc[4][2];
    #pragma unroll
    for (int i = 0; i < 4; ++i)
        #pragma unroll
        for (int j = 0; j < 2; ++j)
            acc[i][j] = (f32x4){0.f, 0.f, 0.f, 0.f};

    const int NK = K >> 5;

    // prologue: tile 0 -> buffer 0
    gload_lds16(Ag0, lA);
    gload_lds16(Ag1, lA + 512);
    gload_lds16(Ag2, lA + 1024);
    gload_lds16(Ag3, lA + 1536);
    gload_lds16(Wg0, lB);
    gload_lds16(Wg1, lB + 512);

    for (int k = 0; k < NK; ++k) {
        const int buf = k & 1;
        if (k + 1 < NK) {
            const int nb = (k + 1) << 5;
            const int nxt = buf ^ 1;
            __hip_bfloat16* dA = lA + nxt * 2048;
            __hip_bfloat16* dB = lB + nxt * 1024;
            // WAR guard: ds_reads of the buffer we overwrite finished (their
            // consumers issued an iteration ago) — drain lgkm to be safe.
            asm volatile("s_waitcnt lgkmcnt(0)" ::: "memory");
            gload_lds16(Ag0 + nb, dA);
            gload_lds16(Ag1 + nb, dA + 512);
            gload_lds16(Ag2 + nb, dA + 1024);
            gload_lds16(Ag3 + nb, dA + 1536);
            gload_lds16(Wg0 + nb, dB);
            gload_lds16(Wg1 + nb, dB + 512);
            asm volatile("s_waitcnt vmcnt(6)" ::: "memory");
        } else {
            asm volatile("s_waitcnt vmcnt(0)" ::: "memory");
        }

        const __hip_bfloat16* Asb = lA + buf * 2048;
        const __hip_bfloat16* Bsb = lB + buf * 1024;
        bf16x8 af[4], bfr[2];
        #pragma unroll
        for (int i = 0; i < 4; ++i)
            af[i] = *(const bf16x8*)&Asb[(i * 16 + r16) * 32 + quad * 8];
        #pragma unroll
        for (int j = 0; j < 2; ++j)
            bfr[j] = *(const bf16x8*)&Bsb[(j * 16 + r16) * 32 + quad * 8];
        #pragma unroll
        for (int i = 0; i < 4; ++i)
            #pragma unroll
            for (int j = 0; j < 2; ++j)
                acc[i][j] = __builtin_amdgcn_mfma_f32_16x16x32_bf16(
                    af[i], bfr[j], acc[i][j], 0, 0, 0);
    }

    #pragma unroll
    for (int i = 0; i < 4; ++i) {
        const int row_base = m0 + i * 16 + quad * 4;
        #pragma unroll
        for (int j = 0; j < 2; ++j) {
            const int col = n0 + j * 16 + r16;
            const float bs = bias[col];
            #pragma unroll
            for (int r = 0; r < 4; ++r) {
                float v = acc[i][j][r] + bs;
                if (SOFTPLUS) v = softplus_f(v);
                const size_t idx = (size_t)(row_base + r) * ldc + col;
                if (OUT_BF16) Cb[idx] = __float2bfloat16(v);
                else          Cf[idx] = v;
            }
        }
    }
}

// ---------------------------------------------------------------------------
// Banded MFMA attention. Block = 16-query tile; wave w = head w.
// ---------------------------------------------------------------------------
#define VT_STRIDE 40   // u16 stride: 80B rows -> 16B aligned

__global__ __launch_bounds__(256) void attn_mfma_kernel(
    const __hip_bfloat16* __restrict__ qb,   // [L, 512]
    const __hip_bfloat16* __restrict__ kb,   // [S+S_PAD, 512], pad rows zero
    const __hip_bfloat16* __restrict__ vb,   // [S+S_PAD, 512], pad rows zero
    __hip_bfloat16* __restrict__ ob)         // [L, 512]
{
    __shared__ __hip_bfloat16 Vt[HEADS][HDIM * VT_STRIDE];  // [dim][src]
    __shared__ __hip_bfloat16 Ps[HEADS][16 * 32];           // [query][src]

    const int t = threadIdx.x;
    const int h = t >> 6;
    const int lane = t & 63;
    const int r16 = lane & 15;
    const int quad = lane >> 4;
    const int l0 = blockIdx.x * 16;

    int i_start = (l0 - 64) / 5;
    if (i_start < 0) i_start = 0;

    // ---- stage V window transposed: Vt[dim][src] ----
    {
        const int s = lane & 31;
        const int half = lane >> 5;
        const __hip_bfloat16* vrow =
            vb + (size_t)(i_start + s) * DIM + h * HDIM + half * 64;
        short* vt = (short*)Vt[h];
        #pragma unroll
        for (int jj = 0; jj < 8; ++jj) {
            bf16x8 v = *(const bf16x8*)(vrow + jj * 8);
            #pragma unroll
            for (int e = 0; e < 8; ++e)
                vt[(half * 64 + jj * 8 + e) * VT_STRIDE + s] = v[e];
        }
    }

    // ---- QK^T: 16 queries x 32 sources ----
    const short* qg = (const short*)qb + (size_t)(l0 + r16) * DIM + h * HDIM + quad * 8;
    const short* kg0 = (const short*)kb + (size_t)(i_start + r16) * DIM + h * HDIM + quad * 8;
    const short* kg1 = kg0 + 16 * DIM;

    f32x4 c0 = {0.f, 0.f, 0.f, 0.f};
    f32x4 c1 = {0.f, 0.f, 0.f, 0.f};
    #pragma unroll
    for (int kk = 0; kk < 4; ++kk) {
        bf16x8 aq = *(const bf16x8*)(qg + kk * 32);
        bf16x8 b0 = *(const bf16x8*)(kg0 + kk * 32);
        bf16x8 b1 = *(const bf16x8*)(kg1 + kk * 32);
        c0 = __builtin_amdgcn_mfma_f32_16x16x32_bf16(aq, b0, c0, 0, 0, 0);
        c1 = __builtin_amdgcn_mfma_f32_16x16x32_bf16(aq, b1, c1, 0, 0, 0);
    }

    // ---- mask + softmax ----
    const float scale = 0.08838834764831845f;   // 1/sqrt(128)
    const int ic0 = i_start + r16;
    const int ic1 = ic0 + 16;
    float recl[4];
    short* ps = (short*)Ps[h];
    #pragma unroll
    for (int r = 0; r < 4; ++r) {
        const int l = l0 + quad * 4 + r;
        const bool a0 = (l >= 5 * ic0 - 64) && (l < 5 * ic0 + 69) && (ic0 < S_LEN);
        const bool a1 = (l >= 5 * ic1 - 64) && (l < 5 * ic1 + 69) && (ic1 < S_LEN);
        float s0 = a0 ? c0[r] * scale : -1e30f;
        float s1 = a1 ? c1[r] * scale : -1e30f;
        float mx = fmaxf(s0, s1);
        #pragma unroll
        for (int o = 8; o; o >>= 1) mx = fmaxf(mx, __shfl_xor(mx, o));
        float e0 = __expf(s0 - mx);
        float e1 = __expf(s1 - mx);
        float sm = e0 + e1;
        #pragma unroll
        for (int o = 8; o; o >>= 1) sm += __shfl_xor(sm, o);
        recl[r] = 1.0f / sm;
        __hip_bfloat16 p0 = __float2bfloat16(e0);
        __hip_bfloat16 p1 = __float2bfloat16(e1);
        ps[(quad * 4 + r) * 32 + r16]      = *(short*)&p0;
        ps[(quad * 4 + r) * 32 + r16 + 16] = *(short*)&p1;
    }

    __syncthreads();

    // ---- PV: P [16x32] x Vt [32 x 128] ----
    bf16x8 ap = *(const bf16x8*)&Ps[h][r16 * 32 + quad * 8];
    #pragma unroll
    for (int nt = 0; nt < 8; ++nt) {
        bf16x8 bv = *(const bf16x8*)&Vt[h][(nt * 16 + r16) * VT_STRIDE + quad * 8];
        f32x4 o = {0.f, 0.f, 0.f, 0.f};
        o = __builtin_amdgcn_mfma_f32_16x16x32_bf16(ap, bv, o, 0, 0, 0);
        #pragma unroll
        for (int r = 0; r < 4; ++r) {
            ob[(size_t)(l0 + quad * 4 + r) * DIM + h * HDIM + nt * 16 + r16] =
                __float2bfloat16(o[r] * recl[r]);
        }
    }
}

// ---------------------------------------------------------------------------
// LayerNorm(attn_out) + residual -> bf16 into padded conv buffer (row r+1)
// ---------------------------------------------------------------------------
__global__ __launch_bounds__(256) void ln_residual_kernel(
    const float* __restrict__ attn_out, const float* __restrict__ residual,
    __hip_bfloat16* __restrict__ hp0)
{
    __shared__ float red[4];
    const int r = blockIdx.x;
    const int t = threadIdx.x;
    const size_t base = (size_t)r * DIM + t * 2;
    float z0 = attn_out[base], z1 = attn_out[base + 1];

    float s = z0 + z1;
    #pragma unroll
    for (int o = 32; o; o >>= 1) s += __shfl_xor(s, o);
    if ((t & 63) == 0) red[t >> 6] = s;
    __syncthreads();
    const float mean = (red[0] + red[1] + red[2] + red[3]) * (1.0f / DIM);
    __syncthreads();

    const float d0 = z0 - mean, d1 = z1 - mean;
    float vq = d0 * d0 + d1 * d1;
    #pragma unroll
    for (int o = 32; o; o >>= 1) vq += __shfl_xor(vq, o);
    if ((t & 63) == 0) red[t >> 6] = vq;
    __syncthreads();
    const float var = (red[0] + red[1] + red[2] + red[3]) * (1.0f / DIM);
    const float rstd = rsqrtf(var + 1e-5f);

    const float y0 = d0 * rstd + residual[base];
    const float y1 = d1 * rstd + residual[base + 1];
    __hip_bfloat16* out = hp0 + (size_t)(r + 1) * DIM + t * 2;
    out[0] = __float2bfloat16(y0);
    out[1] = __float2bfloat16(y1);
}

// ---------------------------------------------------------------------------
// Final: LayerNorm(conv_out + skip_out) -> d_out (f32)
// ---------------------------------------------------------------------------
__global__ __launch_bounds__(256) void final_ln_kernel(
    const float* __restrict__ conv_out, const float* __restrict__ skip_out,
    float* __restrict__ out)
{
    __shared__ float red[4];
    const int r = blockIdx.x;
    const int t = threadIdx.x;
    const size_t base = (size_t)r * DIM + t * 2;
    float z0 = conv_out[base] + skip_out[base];
    float z1 = conv_out[base + 1] + skip_out[base + 1];

    float s = z0 + z1;
    #pragma unroll
    for (int o = 32; o; o >>= 1) s += __shfl_xor(s, o);
    if ((t & 63) == 0) red[t >> 6] = s;
    __syncthreads();
    const float mean = (red[0] + red[1] + red[2] + red[3]) * (1.0f / DIM);
    __syncthreads();

    const float d0 = z0 - mean, d1 = z1 - mean;
    float vq = d0 * d0 + d1 * d1;
    #pragma unroll
    for (int o = 32; o; o >>= 1) vq += __shfl_xor(vq, o);
    if ((t & 63) == 0) red[t >> 6] = vq;
    __syncthreads();
    const float var = (red[0] + red[1] + red[2] + red[3]) * (1.0f / DIM);
    const float rstd = rsqrtf(var + 1e-5f);

    out[base]     = d0 * rstd;
    out[base + 1] = d1 * rstd;
}

// ---------------------------------------------------------------------------
// Staging kernels
// ---------------------------------------------------------------------------
__global__ void build_src_kernel(const float* __restrict__ x,
                                 __hip_bfloat16* __restrict__ src)
{
    int idx = blockIdx.x * 256 + threadIdx.x;
    if (idx >= S_LEN * KDIM_P) return;
    int i = idx / KDIM_P, j = idx % KDIM_P;
    float v;
    if (j < 128)       v = x[i * 128 + j];
    else if (j < KDIM) { int e = j - 128; v = (float)(i & ((2 << e) - 1)) / (float)(1 << e); }
    else               v = 0.f;
    src[idx] = __float2bfloat16(v);
}

__global__ void convert_pad_kernel(const float* __restrict__ src,
                                   __hip_bfloat16* __restrict__ dst,
                                   int R, int C, int Cp)
{
    int idx = blockIdx.x * 256 + threadIdx.x;
    if (idx >= R * Cp) return;
    int r = idx / Cp, c = idx % Cp;
    dst[idx] = __float2bfloat16(c < C ? src[(size_t)r * C + c] : 0.f);
}

// conv_w [3][512][512][3] -> wt [3][512][3*512] as [c][k][ci]
__global__ void conv_wt_kernel(const float* __restrict__ w,
                               __hip_bfloat16* __restrict__ wt)
{
    int idx = blockIdx.x * 256 + threadIdx.x;
    if (idx >= NLAYERS * DIM * CONV_K) return;
    int lc = idx / CONV_K;
    int rem = idx % CONV_K;
    int k = rem / DIM, ci = rem % DIM;
    wt[idx] = __float2bfloat16(w[(size_t)lc * CONV_K + ci * 3 + k]);
}

__global__ void zero_pad_rows_kernel(__hip_bfloat16* hp0, __hip_bfloat16* hp1)
{
    const int t = threadIdx.x;  // 512
    const __hip_bfloat16 z = __float2bfloat16(0.f);
    if      (blockIdx.x == 0) hp0[t] = z;
    else if (blockIdx.x == 1) hp0[(size_t)(L_LEN + 1) * DIM + t] = z;
    else if (blockIdx.x == 2) hp1[t] = z;
    else                      hp1[(size_t)(L_LEN + 1) * DIM + t] = z;
}

// zero the S_PAD overrun rows of k_b and v_b
__global__ void zero_kv_pad_kernel(__hip_bfloat16* k_b, __hip_bfloat16* v_b)
{
    int idx = blockIdx.x * 256 + threadIdx.x;
    if (idx >= S_PAD * DIM) return;
    const __hip_bfloat16 z = __float2bfloat16(0.f);
    k_b[(size_t)S_LEN * DIM + idx] = z;
    v_b[(size_t)S_LEN * DIM + idx] = z;
}

// ---------------------------------------------------------------------------
extern "C" void kernel_launch(void* const* d_in, const int* in_sizes, int n_in,
                              void* d_out, int out_size, void* d_ws, size_t ws_size,
                              hipStream_t stream)
{
    const float* x        = (const float*)d_in[0];
    const float* residual = (const float*)d_in[1];
    const float* proj_w   = (const float*)d_in[2];
    const float* proj_b   = (const float*)d_in[3];
    const float* q_w      = (const float*)d_in[4];
    const float* k_w      = (const float*)d_in[5];
    const float* v_w      = (const float*)d_in[6];
    const float* in_b     = (const float*)d_in[7];
    const float* out_w    = (const float*)d_in[8];
    const float* out_b    = (const float*)d_in[9];
    const float* conv_w   = (const float*)d_in[10];
    const float* conv_b   = (const float*)d_in[11];
    const float* skip_w   = (const float*)d_in[12];
    const float* skip_b   = (const float*)d_in[13];
    float* out = (float*)d_out;

    char* ws = (char*)d_ws;
    size_t off = 0;
    auto alloc = [&](size_t bytes) { char* p = ws + off; off += (bytes + 255) & ~(size_t)255; return p; };

    __hip_bfloat16* src_b   = (__hip_bfloat16*)alloc((size_t)S_LEN * KDIM_P * 2);
    __hip_bfloat16* projw_b = (__hip_bfloat16*)alloc((size_t)DIM * 5 * KDIM_P * 2);
    __hip_bfloat16* qw_b    = (__hip_bfloat16*)alloc((size_t)DIM * DIM * 2);
    __hip_bfloat16* kw_b    = (__hip_bfloat16*)alloc((size_t)DIM * KDIM_P * 2);
    __hip_bfloat16* vw_b    = (__hip_bfloat16*)alloc((size_t)DIM * KDIM_P * 2);
    __hip_bfloat16* outw_b  = (__hip_bfloat16*)alloc((size_t)DIM * DIM * 2);
    __hip_bfloat16* skipw_b = (__hip_bfloat16*)alloc((size_t)DIM * DIM * 2);
    __hip_bfloat16* convwt  = (__hip_bfloat16*)alloc((size_t)NLAYERS * DIM * CONV_K * 2);
    __hip_bfloat16* tgt_b   = (__hip_bfloat16*)alloc((size_t)L_LEN * DIM * 2);
    __hip_bfloat16* q_b     = (__hip_bfloat16*)alloc((size_t)L_LEN * DIM * 2);
    __hip_bfloat16* k_b     = (__hip_bfloat16*)alloc((size_t)(S_LEN + S_PAD) * DIM * 2);
    __hip_bfloat16* v_b     = (__hip_bfloat16*)alloc((size_t)(S_LEN + S_PAD) * DIM * 2);
    __hip_bfloat16* o_b     = (__hip_bfloat16*)alloc((size_t)L_LEN * DIM * 2);
    float*          attn_f  = (float*)alloc((size_t)L_LEN * DIM * 4);
    __hip_bfloat16* hp0     = (__hip_bfloat16*)alloc((size_t)(L_LEN + 2) * DIM * 2);
    __hip_bfloat16* hp1     = (__hip_bfloat16*)alloc((size_t)(L_LEN + 2) * DIM * 2);
    float*          conv_f  = (float*)alloc((size_t)L_LEN * DIM * 4);
    float*          skip_f  = attn_f;
    (void)ws_size; (void)n_in; (void)in_sizes; (void)out_size;

    // --- staging ---
    build_src_kernel<<<(S_LEN * KDIM_P + 255) / 256, 256, 0, stream>>>(x, src_b);
    convert_pad_kernel<<<(DIM * 5 * KDIM_P + 255) / 256, 256, 0, stream>>>(proj_w, projw_b, DIM * 5, KDIM, KDIM_P);
    convert_pad_kernel<<<(DIM * DIM + 255) / 256, 256, 0, stream>>>(q_w, qw_b, DIM, DIM, DIM);
    convert_pad_kernel<<<(DIM * KDIM_P + 255) / 256, 256, 0, stream>>>(k_w, kw_b, DIM, KDIM, KDIM_P);
    convert_pad_kernel<<<(DIM * KDIM_P + 255) / 256, 256, 0, stream>>>(v_w, vw_b, DIM, KDIM, KDIM_P);
    convert_pad_kernel<<<(DIM * DIM + 255) / 256, 256, 0, stream>>>(out_w, outw_b, DIM, DIM, DIM);
    convert_pad_kernel<<<(DIM * DIM + 255) / 256, 256, 0, stream>>>(skip_w, skipw_b, DIM, DIM, DIM);
    conv_wt_kernel<<<(NLAYERS * DIM * CONV_K + 255) / 256, 256, 0, stream>>>(conv_w, convwt);
    zero_pad_rows_kernel<<<4, 512, 0, stream>>>(hp0, hp1);
    zero_kv_pad_kernel<<<(S_PAD * DIM + 255) / 256, 256, 0, stream>>>(k_b, v_b);

    // --- proj: [2048,192] x [2560,192]^T -> [2048,2560] == tgt [10240,512] ---
    gemm_wp<false, true><<<dim3(S_LEN / 128, DIM * 5 / 64), 256, 0, stream>>>(
        src_b, KDIM_P, projw_b, KDIM_P, proj_b, tgt_b, nullptr, DIM * 5, KDIM_P);
    // --- q ---
    gemm_wp<false, true><<<dim3(L_LEN / 128, DIM / 64), 256, 0, stream>>>(
        tgt_b, DIM, qw_b, DIM, in_b, q_b, nullptr, DIM, DIM);
    // --- k, v ---
    gemm_wp<false, true><<<dim3(S_LEN / 128, DIM / 64), 256, 0, stream>>>(
        src_b, KDIM_P, kw_b, KDIM_P, in_b + DIM, k_b, nullptr, DIM, KDIM_P);
    gemm_wp<false, true><<<dim3(S_LEN / 128, DIM / 64), 256, 0, stream>>>(
        src_b, KDIM_P, vw_b, KDIM_P, in_b + 2 * DIM, v_b, nullptr, DIM, KDIM_P);

    // --- banded MFMA attention: 640 blocks x (16 queries x 4 heads) ---
    attn_mfma_kernel<<<L_LEN / 16, 256, 0, stream>>>(q_b, k_b, v_b, o_b);

    // --- out proj -> f32 ---
    gemm_wp<false, false><<<dim3(L_LEN / 128, DIM / 64), 256, 0, stream>>>(
        o_b, DIM, outw_b, DIM, out_b, nullptr, attn_f, DIM, DIM);

    // --- LN + residual -> hp0 rows 1..L (bf16) ---
    ln_residual_kernel<<<L_LEN, 256, 0, stream>>>(attn_f, residual, hp0);

    // --- skip GEMM ---
    gemm_wp<false, false><<<dim3(L_LEN / 128, DIM / 64), 256, 0, stream>>>(
        hp0 + DIM, DIM, skipw_b, DIM, skip_b, nullptr, skip_f, DIM, DIM);

    // --- conv stack: sliding-window GEMMs, K=1536, lda=512 ---
    gemm_wp<true, true><<<dim3(L_LEN / 128, DIM / 64), 256, 0, stream>>>(
        hp0, DIM, convwt, CONV_K, conv_b, hp1 + DIM, nullptr, DIM, CONV_K);
    gemm_wp<true, true><<<dim3(L_LEN / 128, DIM / 64), 256, 0, stream>>>(
        hp1, DIM, convwt + (size_t)DIM * CONV_K, CONV_K, conv_b + DIM, hp0 + DIM, nullptr, DIM, CONV_K);
    gemm_wp<true, false><<<dim3(L_LEN / 128, DIM / 64), 256, 0, stream>>>(
        hp0, DIM, convwt + (size_t)2 * DIM * CONV_K, CONV_K, conv_b + 2 * DIM, nullptr, conv_f, DIM, CONV_K);

    // --- final LN ---
    final_ln_kernel<<<L_LEN, 256, 0, stream>>>(conv_f, skip_f, out);
}

// Round 7
// 347.639 us; speedup vs baseline: 1.1772x; 1.1772x over previous
//
#include <hip/hip_runtime.h>
#include <hip/hip_bf16.h>

// ---------------------------------------------------------------------------
// DecoderBlock: proj -> banded MHA -> LN+residual -> 3x conv1d(softplus) -> LN
// S=2048, L=5S=10240, DIM=512, HEADS=4, hd=128, KDIM=136 (pad->192), EXT=64
// GEMMs: 128x64 block tile, BK=64 (two BK=32 sub-tiles per LDS buffer),
// double-buffered, raw s_barrier + s_waitcnt vmcnt(6). Evidence (R3-R6):
// wall = ~2800 cy per K-iteration regardless of body -> fewer fatter iters.
// Attention: banded one-shot MFMA flash (window <= 30 per 16-query tile).
// ---------------------------------------------------------------------------

#define S_LEN   2048
#define S_PAD   32       // zero pad rows on kv_b for window overrun
#define L_LEN   10240
#define DIM     512
#define KDIM    136
#define KDIM_P  192      // padded to multiple of 64
#define NPOS    8
#define HEADS   4
#define HDIM    128
#define NLAYERS 3
#define CONV_K  1536
#define KV_LD   1024     // fused k|v row stride

typedef __attribute__((ext_vector_type(8))) short bf16x8;
typedef __attribute__((ext_vector_type(4))) float f32x4;

__device__ __forceinline__ float softplus_f(float x) {
    return x > 20.0f ? x : log1pf(__expf(x));
}

__device__ __forceinline__ void gload_lds16(const __hip_bfloat16* g,
                                            __hip_bfloat16* l) {
    __builtin_amdgcn_global_load_lds(
        (const __attribute__((address_space(1))) void*)g,
        (__attribute__((address_space(3))) void*)l, 16, 0, 0);
}

// ---------------------------------------------------------------------------
// GEMM: C[m,n] = act( sum_k A[m*lda+k] * W[n*ldw+k] + bias[n] )
// Block = 128(m) x 64(n), 4 waves 2x2, wave tile 64x32 (4x2 MFMA), BK=64.
// LDS: As[2][2][128][32] (buf, kh) 32 KB + Bs[2][2][64][32] 16 KB = 48 KB.
// Per iter: 6 DMA/wave (tile k+1) -> vmcnt(6) -> barrier -> 12 ds_read +
// 16 MFMA -> lgkmcnt(0) -> barrier. Requires M%128==0, N%64==0, K%64==0.
// ---------------------------------------------------------------------------
template<bool SOFTPLUS, bool OUT_BF16>
__global__ __launch_bounds__(256) void gemm_bk64(
    const __hip_bfloat16* __restrict__ A, int lda,
    const __hip_bfloat16* __restrict__ W, int ldw,
    const float* __restrict__ bias,
    __hip_bfloat16* __restrict__ Cb, float* __restrict__ Cf, int ldc,
    int K)
{
    __shared__ __hip_bfloat16 As[2 * 2 * 128 * 32];   // 32 KB
    __shared__ __hip_bfloat16 Bs[2 * 2 * 64 * 32];    // 16 KB

    const int t = threadIdx.x;
    const int w = t >> 6;
    const int lane = t & 63;
    const int r16 = lane & 15;
    const int quad = lane >> 4;

    const int m0 = blockIdx.x * 128;
    const int n0 = blockIdx.y * 64;
    const int mo = (w >> 1) * 64;   // wave m-offset: 0 or 64
    const int no = (w & 1) * 32;    // wave n-offset: 0 or 32

    // staging: each DMA covers 16 rows x 32 K; lane -> row lane>>2, col (lane&3)*8
    const int srow = w * 16 + (lane >> 2);
    const int scol = (lane & 3) * 8;
    const __hip_bfloat16* Ag0 = A + (size_t)(m0 + srow) * lda + scol;       // group 0
    const __hip_bfloat16* Ag1 = A + (size_t)(m0 + 64 + srow) * lda + scol;  // group 1
    const __hip_bfloat16* Wg  = W + (size_t)(n0 + srow) * ldw + scol;
    __hip_bfloat16* lA0 = &As[(size_t)(w * 16) * 32];          // + buf*8192 + kh*4096
    __hip_bfloat16* lA1 = &As[(size_t)(64 + w * 16) * 32];
    __hip_bfloat16* lB  = &Bs[(size_t)(w * 16) * 32];          // + buf*4096 + kh*2048

    f32x4 acc[4][2];
    #pragma unroll
    for (int i = 0; i < 4; ++i)
        #pragma unroll
        for (int j = 0; j < 2; ++j)
            acc[i][j] = (f32x4){0.f, 0.f, 0.f, 0.f};

    const int NK = K >> 6;

    auto stage = [&](int buf, int k0) {
        #pragma unroll
        for (int kh = 0; kh < 2; ++kh) {
            const int gk = k0 + kh * 32;
            gload_lds16(Ag0 + gk, lA0 + buf * 8192 + kh * 4096);
            gload_lds16(Ag1 + gk, lA1 + buf * 8192 + kh * 4096);
            gload_lds16(Wg  + gk, lB  + buf * 4096 + kh * 2048);
        }
    };

    // prologue: tile 0 -> buffer 0
    stage(0, 0);

    for (int k = 0; k < NK; ++k) {
        const int buf = k & 1;
        if (k + 1 < NK) {
            stage(buf ^ 1, (k + 1) << 6);
            asm volatile("s_waitcnt vmcnt(6)" ::: "memory");
        } else {
            asm volatile("s_waitcnt vmcnt(0)" ::: "memory");
        }
        asm volatile("s_barrier" ::: "memory");

        #pragma unroll
        for (int kh = 0; kh < 2; ++kh) {
            const __hip_bfloat16* Asb = As + buf * 8192 + kh * 4096;
            const __hip_bfloat16* Bsb = Bs + buf * 4096 + kh * 2048;
            bf16x8 af[4], bfr[2];
            #pragma unroll
            for (int i = 0; i < 4; ++i)
                af[i] = *(const bf16x8*)&Asb[(mo + i * 16 + r16) * 32 + quad * 8];
            #pragma unroll
            for (int j = 0; j < 2; ++j)
                bfr[j] = *(const bf16x8*)&Bsb[(no + j * 16 + r16) * 32 + quad * 8];
            #pragma unroll
            for (int i = 0; i < 4; ++i)
                #pragma unroll
                for (int j = 0; j < 2; ++j)
                    acc[i][j] = __builtin_amdgcn_mfma_f32_16x16x32_bf16(
                        af[i], bfr[j], acc[i][j], 0, 0, 0);
        }

        asm volatile("s_waitcnt lgkmcnt(0)" ::: "memory");
        asm volatile("s_barrier" ::: "memory");
    }

    #pragma unroll
    for (int i = 0; i < 4; ++i) {
        const int row_base = m0 + mo + i * 16 + quad * 4;
        #pragma unroll
        for (int j = 0; j < 2; ++j) {
            const int col = n0 + no + j * 16 + r16;
            const float bs = bias[col];
            #pragma unroll
            for (int r = 0; r < 4; ++r) {
                float v = acc[i][j][r] + bs;
                if (SOFTPLUS) v = softplus_f(v);
                const size_t idx = (size_t)(row_base + r) * ldc + col;
                if (OUT_BF16) Cb[idx] = __float2bfloat16(v);
                else          Cf[idx] = v;
            }
        }
    }
}

// ---------------------------------------------------------------------------
// Banded MFMA attention. Block = 16-query tile; wave w = head w.
// k/v live in fused kv_b: k = row*KV_LD + [0,512), v = row*KV_LD + [512,1024).
// ---------------------------------------------------------------------------
#define VT_STRIDE 40   // u16 stride: 80B rows -> 16B aligned

__global__ __launch_bounds__(256) void attn_mfma_kernel(
    const __hip_bfloat16* __restrict__ qb,   // [L, 512]
    const __hip_bfloat16* __restrict__ kb,   // [S+S_PAD, KV_LD] (cols 0-511)
    const __hip_bfloat16* __restrict__ vb,   // same buffer + 512
    __hip_bfloat16* __restrict__ ob)         // [L, 512]
{
    __shared__ __hip_bfloat16 Vt[HEADS][HDIM * VT_STRIDE];  // [dim][src]
    __shared__ __hip_bfloat16 Ps[HEADS][16 * 32];           // [query][src]

    const int t = threadIdx.x;
    const int h = t >> 6;
    const int lane = t & 63;
    const int r16 = lane & 15;
    const int quad = lane >> 4;
    const int l0 = blockIdx.x * 16;

    int i_start = (l0 - 64) / 5;
    if (i_start < 0) i_start = 0;

    // ---- stage V window transposed: Vt[dim][src] ----
    {
        const int s = lane & 31;
        const int half = lane >> 5;
        const __hip_bfloat16* vrow =
            vb + (size_t)(i_start + s) * KV_LD + h * HDIM + half * 64;
        short* vt = (short*)Vt[h];
        #pragma unroll
        for (int jj = 0; jj < 8; ++jj) {
            bf16x8 v = *(const bf16x8*)(vrow + jj * 8);
            #pragma unroll
            for (int e = 0; e < 8; ++e)
                vt[(half * 64 + jj * 8 + e) * VT_STRIDE + s] = v[e];
        }
    }

    // ---- QK^T: 16 queries x 32 sources ----
    const short* qg = (const short*)qb + (size_t)(l0 + r16) * DIM + h * HDIM + quad * 8;
    const short* kg0 = (const short*)kb + (size_t)(i_start + r16) * KV_LD + h * HDIM + quad * 8;
    const short* kg1 = kg0 + 16 * KV_LD;

    f32x4 c0 = {0.f, 0.f, 0.f, 0.f};
    f32x4 c1 = {0.f, 0.f, 0.f, 0.f};
    #pragma unroll
    for (int kk = 0; kk < 4; ++kk) {
        bf16x8 aq = *(const bf16x8*)(qg + kk * 32);
        bf16x8 b0 = *(const bf16x8*)(kg0 + kk * 32);
        bf16x8 b1 = *(const bf16x8*)(kg1 + kk * 32);
        c0 = __builtin_amdgcn_mfma_f32_16x16x32_bf16(aq, b0, c0, 0, 0, 0);
        c1 = __builtin_amdgcn_mfma_f32_16x16x32_bf16(aq, b1, c1, 0, 0, 0);
    }

    // ---- mask + softmax ----
    const float scale = 0.08838834764831845f;   // 1/sqrt(128)
    const int ic0 = i_start + r16;
    const int ic1 = ic0 + 16;
    float recl[4];
    short* ps = (short*)Ps[h];
    #pragma unroll
    for (int r = 0; r < 4; ++r) {
        const int l = l0 + quad * 4 + r;
        const bool a0 = (l >= 5 * ic0 - 64) && (l < 5 * ic0 + 69) && (ic0 < S_LEN);
        const bool a1 = (l >= 5 * ic1 - 64) && (l < 5 * ic1 + 69) && (ic1 < S_LEN);
        float s0 = a0 ? c0[r] * scale : -1e30f;
        float s1 = a1 ? c1[r] * scale : -1e30f;
        float mx = fmaxf(s0, s1);
        #pragma unroll
        for (int o = 8; o; o >>= 1) mx = fmaxf(mx, __shfl_xor(mx, o));
        float e0 = __expf(s0 - mx);
        float e1 = __expf(s1 - mx);
        float sm = e0 + e1;
        #pragma unroll
        for (int o = 8; o; o >>= 1) sm += __shfl_xor(sm, o);
        recl[r] = 1.0f / sm;
        __hip_bfloat16 p0 = __float2bfloat16(e0);
        __hip_bfloat16 p1 = __float2bfloat16(e1);
        ps[(quad * 4 + r) * 32 + r16]      = *(short*)&p0;
        ps[(quad * 4 + r) * 32 + r16 + 16] = *(short*)&p1;
    }

    __syncthreads();

    // ---- PV: P [16x32] x Vt [32 x 128] ----
    bf16x8 ap = *(const bf16x8*)&Ps[h][r16 * 32 + quad * 8];
    #pragma unroll
    for (int nt = 0; nt < 8; ++nt) {
        bf16x8 bv = *(const bf16x8*)&Vt[h][(nt * 16 + r16) * VT_STRIDE + quad * 8];
        f32x4 o = {0.f, 0.f, 0.f, 0.f};
        o = __builtin_amdgcn_mfma_f32_16x16x32_bf16(ap, bv, o, 0, 0, 0);
        #pragma unroll
        for (int r = 0; r < 4; ++r) {
            ob[(size_t)(l0 + quad * 4 + r) * DIM + h * HDIM + nt * 16 + r16] =
                __float2bfloat16(o[r] * recl[r]);
        }
    }
}

// ---------------------------------------------------------------------------
// LayerNorm(attn_out) + residual -> bf16 into padded conv buffer (row r+1)
// ---------------------------------------------------------------------------
__global__ __launch_bounds__(256) void ln_residual_kernel(
    const float* __restrict__ attn_out, const float* __restrict__ residual,
    __hip_bfloat16* __restrict__ hp0)
{
    __shared__ float red[4];
    const int r = blockIdx.x;
    const int t = threadIdx.x;
    const size_t base = (size_t)r * DIM + t * 2;
    float z0 = attn_out[base], z1 = attn_out[base + 1];

    float s = z0 + z1;
    #pragma unroll
    for (int o = 32; o; o >>= 1) s += __shfl_xor(s, o);
    if ((t & 63) == 0) red[t >> 6] = s;
    __syncthreads();
    const float mean = (red[0] + red[1] + red[2] + red[3]) * (1.0f / DIM);
    __syncthreads();

    const float d0 = z0 - mean, d1 = z1 - mean;
    float vq = d0 * d0 + d1 * d1;
    #pragma unroll
    for (int o = 32; o; o >>= 1) vq += __shfl_xor(vq, o);
    if ((t & 63) == 0) red[t >> 6] = vq;
    __syncthreads();
    const float var = (red[0] + red[1] + red[2] + red[3]) * (1.0f / DIM);
    const float rstd = rsqrtf(var + 1e-5f);

    const float y0 = d0 * rstd + residual[base];
    const float y1 = d1 * rstd + residual[base + 1];
    __hip_bfloat16* out = hp0 + (size_t)(r + 1) * DIM + t * 2;
    out[0] = __float2bfloat16(y0);
    out[1] = __float2bfloat16(y1);
}

// ---------------------------------------------------------------------------
// Final: LayerNorm(conv_out + skip_out) -> d_out (f32)
// ---------------------------------------------------------------------------
__global__ __launch_bounds__(256) void final_ln_kernel(
    const float* __restrict__ conv_out, const float* __restrict__ skip_out,
    float* __restrict__ out)
{
    __shared__ float red[4];
    const int r = blockIdx.x;
    const int t = threadIdx.x;
    const size_t base = (size_t)r * DIM + t * 2;
    float z0 = conv_out[base] + skip_out[base];
    float z1 = conv_out[base + 1] + skip_out[base + 1];

    float s = z0 + z1;
    #pragma unroll
    for (int o = 32; o; o >>= 1) s += __shfl_xor(s, o);
    if ((t & 63) == 0) red[t >> 6] = s;
    __syncthreads();
    const float mean = (red[0] + red[1] + red[2] + red[3]) * (1.0f / DIM);
    __syncthreads();

    const float d0 = z0 - mean, d1 = z1 - mean;
    float vq = d0 * d0 + d1 * d1;
    #pragma unroll
    for (int o = 32; o; o >>= 1) vq += __shfl_xor(vq, o);
    if ((t & 63) == 0) red[t >> 6] = vq;
    __syncthreads();
    const float var = (red[0] + red[1] + red[2] + red[3]) * (1.0f / DIM);
    const float rstd = rsqrtf(var + 1e-5f);

    out[base]     = d0 * rstd;
    out[base + 1] = d1 * rstd;
}

// ---------------------------------------------------------------------------
// Staging kernels
// ---------------------------------------------------------------------------
__global__ void build_src_kernel(const float* __restrict__ x,
                                 __hip_bfloat16* __restrict__ src)
{
    int idx = blockIdx.x * 256 + threadIdx.x;
    if (idx >= S_LEN * KDIM_P) return;
    int i = idx / KDIM_P, j = idx % KDIM_P;
    float v;
    if (j < 128)       v = x[i * 128 + j];
    else if (j < KDIM) { int e = j - 128; v = (float)(i & ((2 << e) - 1)) / (float)(1 << e); }
    else               v = 0.f;
    src[idx] = __float2bfloat16(v);
}

__global__ void convert_pad_kernel(const float* __restrict__ src,
                                   __hip_bfloat16* __restrict__ dst,
                                   int R, int C, int Cp)
{
    int idx = blockIdx.x * 256 + threadIdx.x;
    if (idx >= R * Cp) return;
    int r = idx / Cp, c = idx % Cp;
    dst[idx] = __float2bfloat16(c < C ? src[(size_t)r * C + c] : 0.f);
}

// conv_w [3][512][512][3] -> wt [3][512][3*512] as [c][k][ci]
__global__ void conv_wt_kernel(const float* __restrict__ w,
                               __hip_bfloat16* __restrict__ wt)
{
    int idx = blockIdx.x * 256 + threadIdx.x;
    if (idx >= NLAYERS * DIM * CONV_K) return;
    int lc = idx / CONV_K;
    int rem = idx % CONV_K;
    int k = rem / DIM, ci = rem % DIM;
    wt[idx] = __float2bfloat16(w[(size_t)lc * CONV_K + ci * 3 + k]);
}

__global__ void zero_pad_rows_kernel(__hip_bfloat16* hp0, __hip_bfloat16* hp1)
{
    const int t = threadIdx.x;  // 512
    const __hip_bfloat16 z = __float2bfloat16(0.f);
    if      (blockIdx.x == 0) hp0[t] = z;
    else if (blockIdx.x == 1) hp0[(size_t)(L_LEN + 1) * DIM + t] = z;
    else if (blockIdx.x == 2) hp1[t] = z;
    else                      hp1[(size_t)(L_LEN + 1) * DIM + t] = z;
}

// zero the S_PAD overrun rows of kv_b (full KV_LD width)
__global__ void zero_kv_pad_kernel(__hip_bfloat16* kv_b)
{
    int idx = blockIdx.x * 256 + threadIdx.x;
    if (idx >= S_PAD * KV_LD) return;
    kv_b[(size_t)S_LEN * KV_LD + idx] = __float2bfloat16(0.f);
}

// ---------------------------------------------------------------------------
extern "C" void kernel_launch(void* const* d_in, const int* in_sizes, int n_in,
                              void* d_out, int out_size, void* d_ws, size_t ws_size,
                              hipStream_t stream)
{
    const float* x        = (const float*)d_in[0];
    const float* residual = (const float*)d_in[1];
    const float* proj_w   = (const float*)d_in[2];
    const float* proj_b   = (const float*)d_in[3];
    const float* q_w      = (const float*)d_in[4];
    const float* k_w      = (const float*)d_in[5];
    const float* v_w      = (const float*)d_in[6];
    const float* in_b     = (const float*)d_in[7];
    const float* out_w    = (const float*)d_in[8];
    const float* out_b    = (const float*)d_in[9];
    const float* conv_w   = (const float*)d_in[10];
    const float* conv_b   = (const float*)d_in[11];
    const float* skip_w   = (const float*)d_in[12];
    const float* skip_b   = (const float*)d_in[13];
    float* out = (float*)d_out;

    char* ws = (char*)d_ws;
    size_t off = 0;
    auto alloc = [&](size_t bytes) { char* p = ws + off; off += (bytes + 255) & ~(size_t)255; return p; };

    __hip_bfloat16* src_b   = (__hip_bfloat16*)alloc((size_t)S_LEN * KDIM_P * 2);
    __hip_bfloat16* projw_b = (__hip_bfloat16*)alloc((size_t)DIM * 5 * KDIM_P * 2);
    __hip_bfloat16* qw_b    = (__hip_bfloat16*)alloc((size_t)DIM * DIM * 2);
    __hip_bfloat16* kvw_b   = (__hip_bfloat16*)alloc((size_t)KV_LD * KDIM_P * 2);
    __hip_bfloat16* outw_b  = (__hip_bfloat16*)alloc((size_t)DIM * DIM * 2);
    __hip_bfloat16* skipw_b = (__hip_bfloat16*)alloc((size_t)DIM * DIM * 2);
    __hip_bfloat16* convwt  = (__hip_bfloat16*)alloc((size_t)NLAYERS * DIM * CONV_K * 2);
    __hip_bfloat16* tgt_b   = (__hip_bfloat16*)alloc((size_t)L_LEN * DIM * 2);
    __hip_bfloat16* q_b     = (__hip_bfloat16*)alloc((size_t)L_LEN * DIM * 2);
    __hip_bfloat16* kv_b    = (__hip_bfloat16*)alloc((size_t)(S_LEN + S_PAD) * KV_LD * 2);
    __hip_bfloat16* o_b     = (__hip_bfloat16*)alloc((size_t)L_LEN * DIM * 2);
    float*          attn_f  = (float*)alloc((size_t)L_LEN * DIM * 4);
    __hip_bfloat16* hp0     = (__hip_bfloat16*)alloc((size_t)(L_LEN + 2) * DIM * 2);
    __hip_bfloat16* hp1     = (__hip_bfloat16*)alloc((size_t)(L_LEN + 2) * DIM * 2);
    float*          conv_f  = (float*)alloc((size_t)L_LEN * DIM * 4);
    float*          skip_f  = attn_f;   // alias: attn_out dead after LN
    (void)ws_size; (void)n_in; (void)in_sizes; (void)out_size;

    // --- staging ---
    build_src_kernel<<<(S_LEN * KDIM_P + 255) / 256, 256, 0, stream>>>(x, src_b);
    convert_pad_kernel<<<(DIM * 5 * KDIM_P + 255) / 256, 256, 0, stream>>>(proj_w, projw_b, DIM * 5, KDIM, KDIM_P);
    convert_pad_kernel<<<(DIM * DIM + 255) / 256, 256, 0, stream>>>(q_w, qw_b, DIM, DIM, DIM);
    convert_pad_kernel<<<(DIM * KDIM_P + 255) / 256, 256, 0, stream>>>(k_w, kvw_b, DIM, KDIM, KDIM_P);
    convert_pad_kernel<<<(DIM * KDIM_P + 255) / 256, 256, 0, stream>>>(v_w, kvw_b + (size_t)DIM * KDIM_P, DIM, KDIM, KDIM_P);
    convert_pad_kernel<<<(DIM * DIM + 255) / 256, 256, 0, stream>>>(out_w, outw_b, DIM, DIM, DIM);
    convert_pad_kernel<<<(DIM * DIM + 255) / 256, 256, 0, stream>>>(skip_w, skipw_b, DIM, DIM, DIM);
    conv_wt_kernel<<<(NLAYERS * DIM * CONV_K + 255) / 256, 256, 0, stream>>>(conv_w, convwt);
    zero_pad_rows_kernel<<<4, 512, 0, stream>>>(hp0, hp1);
    zero_kv_pad_kernel<<<(S_PAD * KV_LD + 255) / 256, 256, 0, stream>>>(kv_b);

    // --- proj: [2048,192] x [2560,192]^T (NK=3) -> tgt [10240,512] ---
    gemm_bk64<false, true><<<dim3(S_LEN / 128, DIM * 5 / 64), 256, 0, stream>>>(
        src_b, KDIM_P, projw_b, KDIM_P, proj_b, tgt_b, nullptr, DIM * 5, KDIM_P);
    // --- q (NK=8) ---
    gemm_bk64<false, true><<<dim3(L_LEN / 128, DIM / 64), 256, 0, stream>>>(
        tgt_b, DIM, qw_b, DIM, in_b, q_b, nullptr, DIM, DIM);
    // --- fused k|v: [2048,192] x [1024,192]^T -> kv_b [2048,1024] (NK=3) ---
    gemm_bk64<false, true><<<dim3(S_LEN / 128, KV_LD / 64), 256, 0, stream>>>(
        src_b, KDIM_P, kvw_b, KDIM_P, in_b + DIM, kv_b, nullptr, KV_LD, KDIM_P);

    // --- banded MFMA attention ---
    attn_mfma_kernel<<<L_LEN / 16, 256, 0, stream>>>(q_b, kv_b, kv_b + DIM, o_b);

    // --- out proj -> f32 (NK=8) ---
    gemm_bk64<false, false><<<dim3(L_LEN / 128, DIM / 64), 256, 0, stream>>>(
        o_b, DIM, outw_b, DIM, out_b, nullptr, attn_f, DIM, DIM);

    // --- LN + residual -> hp0 rows 1..L (bf16) ---
    ln_residual_kernel<<<L_LEN, 256, 0, stream>>>(attn_f, residual, hp0);

    // --- skip GEMM (NK=8) ---
    gemm_bk64<false, false><<<dim3(L_LEN / 128, DIM / 64), 256, 0, stream>>>(
        hp0 + DIM, DIM, skipw_b, DIM, skip_b, nullptr, skip_f, DIM, DIM);

    // --- conv stack: sliding-window GEMMs, K=1536 (NK=24), lda=512 ---
    gemm_bk64<true, true><<<dim3(L_LEN / 128, DIM / 64), 256, 0, stream>>>(
        hp0, DIM, convwt, CONV_K, conv_b, hp1 + DIM, nullptr, DIM, CONV_K);
    gemm_bk64<true, true><<<dim3(L_LEN / 128, DIM / 64), 256, 0, stream>>>(
        hp1, DIM, convwt + (size_t)DIM * CONV_K, CONV_K, conv_b + DIM, hp0 + DIM, nullptr, DIM, CONV_K);
    gemm_bk64<true, false><<<dim3(L_LEN / 128, DIM / 64), 256, 0, stream>>>(
        hp0, DIM, convwt + (size_t)2 * DIM * CONV_K, CONV_K, conv_b + 2 * DIM, nullptr, conv_f, DIM, CONV_K);

    // --- final LN ---
    final_ln_kernel<<<L_LEN, 256, 0, stream>>>(conv_f, skip_f, out);
}

// Round 8
// 298.027 us; speedup vs baseline: 1.3732x; 1.1665x over previous
//
#include <hip/hip_runtime.h>
#include <hip/hip_bf16.h>

// ---------------------------------------------------------------------------
// DecoderBlock: proj -> banded MHA -> LN+residual -> 3x conv1d(softplus) -> LN
// S=2048, L=5S=10240, DIM=512, HEADS=4, hd=128, KDIM=136 (pad->192), EXT=64
// GEMMs: 128x64 tile, BK=64, double-buffered LDS staging + COALESCED EPILOGUE
// (acc -> LDS f32 -> full-line vectorized stores). Evidence R7: GEMM time was
// M*N-proportional (K-independent) -> scattered epilogue stores were the cost.
// Attention: banded one-shot MFMA flash (window <= 30 per 16-query tile).
// ---------------------------------------------------------------------------

#define S_LEN   2048
#define S_PAD   32       // zero pad rows on kv_b for window overrun
#define L_LEN   10240
#define DIM     512
#define KDIM    136
#define KDIM_P  192      // padded to multiple of 64
#define NPOS    8
#define HEADS   4
#define HDIM    128
#define NLAYERS 3
#define CONV_K  1536
#define KV_LD   1024     // fused k|v row stride
#define CS_LD   68       // f32 epilogue staging stride (16B-aligned rows)

typedef __attribute__((ext_vector_type(8))) short bf16x8;
typedef __attribute__((ext_vector_type(4))) float f32x4;

__device__ __forceinline__ float softplus_f(float x) {
    // fast transcendental path; bf16-scale tolerance
    if (x > 15.0f) return x;
    return __logf(1.0f + __expf(x));
}

__device__ __forceinline__ void gload_lds16(const __hip_bfloat16* g,
                                            __hip_bfloat16* l) {
    __builtin_amdgcn_global_load_lds(
        (const __attribute__((address_space(1))) void*)g,
        (__attribute__((address_space(3))) void*)l, 16, 0, 0);
}

// ---------------------------------------------------------------------------
// GEMM: C[m,n] = act( sum_k A[m*lda+k] * W[n*ldw+k] + bias[n] )
// Block = 128(m) x 64(n), 4 waves 2x2, wave tile 64x32 (4x2 MFMA), BK=64.
// LDS: As[2][2][128][32] 32 KB + Bs[2][2][64][32] 16 KB = 48 KB; after the
// K-loop the same memory is reused as Cs[128][CS_LD] f32 for the coalesced
// epilogue. Requires M%128==0, N%64==0, K%64==0, ldc*elt 16B-aligned.
// ---------------------------------------------------------------------------
template<bool SOFTPLUS, bool OUT_BF16>
__global__ __launch_bounds__(256) void gemm_bk64(
    const __hip_bfloat16* __restrict__ A, int lda,
    const __hip_bfloat16* __restrict__ W, int ldw,
    const float* __restrict__ bias,
    __hip_bfloat16* __restrict__ Cb, float* __restrict__ Cf, int ldc,
    int K)
{
    __shared__ __align__(16) char smem[49152];
    __hip_bfloat16* As = (__hip_bfloat16*)smem;              // 32 KB
    __hip_bfloat16* Bs = (__hip_bfloat16*)(smem + 32768);    // 16 KB
    float*          Cs = (float*)smem;                       // 128*68*4 = 34816 B

    const int t = threadIdx.x;
    const int w = t >> 6;
    const int lane = t & 63;
    const int r16 = lane & 15;
    const int quad = lane >> 4;

    const int m0 = blockIdx.x * 128;
    const int n0 = blockIdx.y * 64;
    const int mo = (w >> 1) * 64;   // wave m-offset: 0 or 64
    const int no = (w & 1) * 32;    // wave n-offset: 0 or 32

    // staging: each DMA covers 16 rows x 32 K; lane -> row lane>>2, col (lane&3)*8
    const int srow = w * 16 + (lane >> 2);
    const int scol = (lane & 3) * 8;
    const __hip_bfloat16* Ag0 = A + (size_t)(m0 + srow) * lda + scol;
    const __hip_bfloat16* Ag1 = A + (size_t)(m0 + 64 + srow) * lda + scol;
    const __hip_bfloat16* Wg  = W + (size_t)(n0 + srow) * ldw + scol;
    __hip_bfloat16* lA0 = &As[(size_t)(w * 16) * 32];          // + buf*8192 + kh*4096
    __hip_bfloat16* lA1 = &As[(size_t)(64 + w * 16) * 32];
    __hip_bfloat16* lB  = &Bs[(size_t)(w * 16) * 32];          // + buf*4096 + kh*2048

    f32x4 acc[4][2];
    #pragma unroll
    for (int i = 0; i < 4; ++i)
        #pragma unroll
        for (int j = 0; j < 2; ++j)
            acc[i][j] = (f32x4){0.f, 0.f, 0.f, 0.f};

    const int NK = K >> 6;

    auto stage = [&](int buf, int k0) {
        #pragma unroll
        for (int kh = 0; kh < 2; ++kh) {
            const int gk = k0 + kh * 32;
            gload_lds16(Ag0 + gk, lA0 + buf * 8192 + kh * 4096);
            gload_lds16(Ag1 + gk, lA1 + buf * 8192 + kh * 4096);
            gload_lds16(Wg  + gk, lB  + buf * 4096 + kh * 2048);
        }
    };

    stage(0, 0);

    for (int k = 0; k < NK; ++k) {
        const int buf = k & 1;
        if (k + 1 < NK) {
            stage(buf ^ 1, (k + 1) << 6);
            asm volatile("s_waitcnt vmcnt(6)" ::: "memory");
        } else {
            asm volatile("s_waitcnt vmcnt(0)" ::: "memory");
        }
        asm volatile("s_barrier" ::: "memory");

        #pragma unroll
        for (int kh = 0; kh < 2; ++kh) {
            const __hip_bfloat16* Asb = As + buf * 8192 + kh * 4096;
            const __hip_bfloat16* Bsb = Bs + buf * 4096 + kh * 2048;
            bf16x8 af[4], bfr[2];
            #pragma unroll
            for (int i = 0; i < 4; ++i)
                af[i] = *(const bf16x8*)&Asb[(mo + i * 16 + r16) * 32 + quad * 8];
            #pragma unroll
            for (int j = 0; j < 2; ++j)
                bfr[j] = *(const bf16x8*)&Bsb[(no + j * 16 + r16) * 32 + quad * 8];
            #pragma unroll
            for (int i = 0; i < 4; ++i)
                #pragma unroll
                for (int j = 0; j < 2; ++j)
                    acc[i][j] = __builtin_amdgcn_mfma_f32_16x16x32_bf16(
                        af[i], bfr[j], acc[i][j], 0, 0, 0);
        }

        asm volatile("s_waitcnt lgkmcnt(0)" ::: "memory");
        asm volatile("s_barrier" ::: "memory");
    }

    // ---- epilogue: acc -> Cs (f32, bias+act applied) ----
    #pragma unroll
    for (int i = 0; i < 4; ++i) {
        const int rl = mo + i * 16 + quad * 4;
        #pragma unroll
        for (int j = 0; j < 2; ++j) {
            const int cl = no + j * 16 + r16;
            const float bs = bias[n0 + cl];
            #pragma unroll
            for (int r = 0; r < 4; ++r) {
                float v = acc[i][j][r] + bs;
                if (SOFTPLUS) v = softplus_f(v);
                Cs[(rl + r) * CS_LD + cl] = v;
            }
        }
    }
    __syncthreads();

    // ---- coalesced stores: full 128B lines per 8 (bf16) / 4 (f32) rows ----
    if (OUT_BF16) {
        const int rsub = lane >> 3;          // 0..7
        const int c8 = (lane & 7) * 8;       // 8 bf16 per lane
        #pragma unroll
        for (int it = 0; it < 4; ++it) {
            const int rl = w * 32 + it * 8 + rsub;
            const float* src = &Cs[rl * CS_LD + c8];
            f32x4 a = *(const f32x4*)src;
            f32x4 b = *(const f32x4*)(src + 4);
            bf16x8 o;
            #pragma unroll
            for (int e = 0; e < 4; ++e) {
                __hip_bfloat16 x = __float2bfloat16(a[e]);
                __hip_bfloat16 y = __float2bfloat16(b[e]);
                o[e]     = *(short*)&x;
                o[e + 4] = *(short*)&y;
            }
            *(bf16x8*)(Cb + (size_t)(m0 + rl) * ldc + n0 + c8) = o;
        }
    } else {
        const int rsub = lane >> 4;          // 0..3
        const int c4 = (lane & 15) * 4;      // 4 f32 per lane
        #pragma unroll
        for (int it = 0; it < 8; ++it) {
            const int rl = w * 32 + it * 4 + rsub;
            f32x4 a = *(const f32x4*)&Cs[rl * CS_LD + c4];
            *(f32x4*)(Cf + (size_t)(m0 + rl) * ldc + n0 + c4) = a;
        }
    }
}

// ---------------------------------------------------------------------------
// Banded MFMA attention. Block = 16-query tile; wave w = head w.
// k/v live in fused kv_b: k = row*KV_LD + [0,512), v = row*KV_LD + [512,1024).
// ---------------------------------------------------------------------------
#define VT_STRIDE 40   // u16 stride: 80B rows -> 16B aligned

__global__ __launch_bounds__(256) void attn_mfma_kernel(
    const __hip_bfloat16* __restrict__ qb,   // [L, 512]
    const __hip_bfloat16* __restrict__ kb,   // [S+S_PAD, KV_LD] (cols 0-511)
    const __hip_bfloat16* __restrict__ vb,   // same buffer + 512
    __hip_bfloat16* __restrict__ ob)         // [L, 512]
{
    __shared__ __hip_bfloat16 Vt[HEADS][HDIM * VT_STRIDE];  // [dim][src]
    __shared__ __hip_bfloat16 Ps[HEADS][16 * 32];           // [query][src]

    const int t = threadIdx.x;
    const int h = t >> 6;
    const int lane = t & 63;
    const int r16 = lane & 15;
    const int quad = lane >> 4;
    const int l0 = blockIdx.x * 16;

    int i_start = (l0 - 64) / 5;
    if (i_start < 0) i_start = 0;

    // ---- stage V window transposed: Vt[dim][src] ----
    {
        const int s = lane & 31;
        const int half = lane >> 5;
        const __hip_bfloat16* vrow =
            vb + (size_t)(i_start + s) * KV_LD + h * HDIM + half * 64;
        short* vt = (short*)Vt[h];
        #pragma unroll
        for (int jj = 0; jj < 8; ++jj) {
            bf16x8 v = *(const bf16x8*)(vrow + jj * 8);
            #pragma unroll
            for (int e = 0; e < 8; ++e)
                vt[(half * 64 + jj * 8 + e) * VT_STRIDE + s] = v[e];
        }
    }

    // ---- QK^T: 16 queries x 32 sources ----
    const short* qg = (const short*)qb + (size_t)(l0 + r16) * DIM + h * HDIM + quad * 8;
    const short* kg0 = (const short*)kb + (size_t)(i_start + r16) * KV_LD + h * HDIM + quad * 8;
    const short* kg1 = kg0 + 16 * KV_LD;

    f32x4 c0 = {0.f, 0.f, 0.f, 0.f};
    f32x4 c1 = {0.f, 0.f, 0.f, 0.f};
    #pragma unroll
    for (int kk = 0; kk < 4; ++kk) {
        bf16x8 aq = *(const bf16x8*)(qg + kk * 32);
        bf16x8 b0 = *(const bf16x8*)(kg0 + kk * 32);
        bf16x8 b1 = *(const bf16x8*)(kg1 + kk * 32);
        c0 = __builtin_amdgcn_mfma_f32_16x16x32_bf16(aq, b0, c0, 0, 0, 0);
        c1 = __builtin_amdgcn_mfma_f32_16x16x32_bf16(aq, b1, c1, 0, 0, 0);
    }

    // ---- mask + softmax ----
    const float scale = 0.08838834764831845f;   // 1/sqrt(128)
    const int ic0 = i_start + r16;
    const int ic1 = ic0 + 16;
    float recl[4];
    short* ps = (short*)Ps[h];
    #pragma unroll
    for (int r = 0; r < 4; ++r) {
        const int l = l0 + quad * 4 + r;
        const bool a0 = (l >= 5 * ic0 - 64) && (l < 5 * ic0 + 69) && (ic0 < S_LEN);
        const bool a1 = (l >= 5 * ic1 - 64) && (l < 5 * ic1 + 69) && (ic1 < S_LEN);
        float s0 = a0 ? c0[r] * scale : -1e30f;
        float s1 = a1 ? c1[r] * scale : -1e30f;
        float mx = fmaxf(s0, s1);
        #pragma unroll
        for (int o = 8; o; o >>= 1) mx = fmaxf(mx, __shfl_xor(mx, o));
        float e0 = __expf(s0 - mx);
        float e1 = __expf(s1 - mx);
        float sm = e0 + e1;
        #pragma unroll
        for (int o = 8; o; o >>= 1) sm += __shfl_xor(sm, o);
        recl[r] = 1.0f / sm;
        __hip_bfloat16 p0 = __float2bfloat16(e0);
        __hip_bfloat16 p1 = __float2bfloat16(e1);
        ps[(quad * 4 + r) * 32 + r16]      = *(short*)&p0;
        ps[(quad * 4 + r) * 32 + r16 + 16] = *(short*)&p1;
    }

    __syncthreads();

    // ---- PV: P [16x32] x Vt [32 x 128] ----
    bf16x8 ap = *(const bf16x8*)&Ps[h][r16 * 32 + quad * 8];
    #pragma unroll
    for (int nt = 0; nt < 8; ++nt) {
        bf16x8 bv = *(const bf16x8*)&Vt[h][(nt * 16 + r16) * VT_STRIDE + quad * 8];
        f32x4 o = {0.f, 0.f, 0.f, 0.f};
        o = __builtin_amdgcn_mfma_f32_16x16x32_bf16(ap, bv, o, 0, 0, 0);
        #pragma unroll
        for (int r = 0; r < 4; ++r) {
            ob[(size_t)(l0 + quad * 4 + r) * DIM + h * HDIM + nt * 16 + r16] =
                __float2bfloat16(o[r] * recl[r]);
        }
    }
}

// ---------------------------------------------------------------------------
// LayerNorm(attn_out) + residual -> bf16 into padded conv buffer (row r+1)
// ---------------------------------------------------------------------------
__global__ __launch_bounds__(256) void ln_residual_kernel(
    const float* __restrict__ attn_out, const float* __restrict__ residual,
    __hip_bfloat16* __restrict__ hp0)
{
    __shared__ float red[4];
    const int r = blockIdx.x;
    const int t = threadIdx.x;
    const size_t base = (size_t)r * DIM + t * 2;
    float z0 = attn_out[base], z1 = attn_out[base + 1];

    float s = z0 + z1;
    #pragma unroll
    for (int o = 32; o; o >>= 1) s += __shfl_xor(s, o);
    if ((t & 63) == 0) red[t >> 6] = s;
    __syncthreads();
    const float mean = (red[0] + red[1] + red[2] + red[3]) * (1.0f / DIM);
    __syncthreads();

    const float d0 = z0 - mean, d1 = z1 - mean;
    float vq = d0 * d0 + d1 * d1;
    #pragma unroll
    for (int o = 32; o; o >>= 1) vq += __shfl_xor(vq, o);
    if ((t & 63) == 0) red[t >> 6] = vq;
    __syncthreads();
    const float var = (red[0] + red[1] + red[2] + red[3]) * (1.0f / DIM);
    const float rstd = rsqrtf(var + 1e-5f);

    const float y0 = d0 * rstd + residual[base];
    const float y1 = d1 * rstd + residual[base + 1];
    __hip_bfloat16* out = hp0 + (size_t)(r + 1) * DIM + t * 2;
    out[0] = __float2bfloat16(y0);
    out[1] = __float2bfloat16(y1);
}

// ---------------------------------------------------------------------------
// Final: LayerNorm(conv_out + skip_out) -> d_out (f32)
// ---------------------------------------------------------------------------
__global__ __launch_bounds__(256) void final_ln_kernel(
    const float* __restrict__ conv_out, const float* __restrict__ skip_out,
    float* __restrict__ out)
{
    __shared__ float red[4];
    const int r = blockIdx.x;
    const int t = threadIdx.x;
    const size_t base = (size_t)r * DIM + t * 2;
    float z0 = conv_out[base] + skip_out[base];
    float z1 = conv_out[base + 1] + skip_out[base + 1];

    float s = z0 + z1;
    #pragma unroll
    for (int o = 32; o; o >>= 1) s += __shfl_xor(s, o);
    if ((t & 63) == 0) red[t >> 6] = s;
    __syncthreads();
    const float mean = (red[0] + red[1] + red[2] + red[3]) * (1.0f / DIM);
    __syncthreads();

    const float d0 = z0 - mean, d1 = z1 - mean;
    float vq = d0 * d0 + d1 * d1;
    #pragma unroll
    for (int o = 32; o; o >>= 1) vq += __shfl_xor(vq, o);
    if ((t & 63) == 0) red[t >> 6] = vq;
    __syncthreads();
    const float var = (red[0] + red[1] + red[2] + red[3]) * (1.0f / DIM);
    const float rstd = rsqrtf(var + 1e-5f);

    out[base]     = d0 * rstd;
    out[base + 1] = d1 * rstd;
}

// ---------------------------------------------------------------------------
// Staging kernels
// ---------------------------------------------------------------------------
__global__ void build_src_kernel(const float* __restrict__ x,
                                 __hip_bfloat16* __restrict__ src)
{
    int idx = blockIdx.x * 256 + threadIdx.x;
    if (idx >= S_LEN * KDIM_P) return;
    int i = idx / KDIM_P, j = idx % KDIM_P;
    float v;
    if (j < 128)       v = x[i * 128 + j];
    else if (j < KDIM) { int e = j - 128; v = (float)(i & ((2 << e) - 1)) / (float)(1 << e); }
    else               v = 0.f;
    src[idx] = __float2bfloat16(v);
}

__global__ void convert_pad_kernel(const float* __restrict__ src,
                                   __hip_bfloat16* __restrict__ dst,
                                   int R, int C, int Cp)
{
    int idx = blockIdx.x * 256 + threadIdx.x;
    if (idx >= R * Cp) return;
    int r = idx / Cp, c = idx % Cp;
    dst[idx] = __float2bfloat16(c < C ? src[(size_t)r * C + c] : 0.f);
}

// conv_w [3][512][512][3] -> wt [3][512][3*512] as [c][k][ci]
__global__ void conv_wt_kernel(const float* __restrict__ w,
                               __hip_bfloat16* __restrict__ wt)
{
    int idx = blockIdx.x * 256 + threadIdx.x;
    if (idx >= NLAYERS * DIM * CONV_K) return;
    int lc = idx / CONV_K;
    int rem = idx % CONV_K;
    int k = rem / DIM, ci = rem % DIM;
    wt[idx] = __float2bfloat16(w[(size_t)lc * CONV_K + ci * 3 + k]);
}

__global__ void zero_pad_rows_kernel(__hip_bfloat16* hp0, __hip_bfloat16* hp1)
{
    const int t = threadIdx.x;  // 512
    const __hip_bfloat16 z = __float2bfloat16(0.f);
    if      (blockIdx.x == 0) hp0[t] = z;
    else if (blockIdx.x == 1) hp0[(size_t)(L_LEN + 1) * DIM + t] = z;
    else if (blockIdx.x == 2) hp1[t] = z;
    else                      hp1[(size_t)(L_LEN + 1) * DIM + t] = z;
}

// zero the S_PAD overrun rows of kv_b (full KV_LD width)
__global__ void zero_kv_pad_kernel(__hip_bfloat16* kv_b)
{
    int idx = blockIdx.x * 256 + threadIdx.x;
    if (idx >= S_PAD * KV_LD) return;
    kv_b[(size_t)S_LEN * KV_LD + idx] = __float2bfloat16(0.f);
}

// ---------------------------------------------------------------------------
extern "C" void kernel_launch(void* const* d_in, const int* in_sizes, int n_in,
                              void* d_out, int out_size, void* d_ws, size_t ws_size,
                              hipStream_t stream)
{
    const float* x        = (const float*)d_in[0];
    const float* residual = (const float*)d_in[1];
    const float* proj_w   = (const float*)d_in[2];
    const float* proj_b   = (const float*)d_in[3];
    const float* q_w      = (const float*)d_in[4];
    const float* k_w      = (const float*)d_in[5];
    const float* v_w      = (const float*)d_in[6];
    const float* in_b     = (const float*)d_in[7];
    const float* out_w    = (const float*)d_in[8];
    const float* out_b    = (const float*)d_in[9];
    const float* conv_w   = (const float*)d_in[10];
    const float* conv_b   = (const float*)d_in[11];
    const float* skip_w   = (const float*)d_in[12];
    const float* skip_b   = (const float*)d_in[13];
    float* out = (float*)d_out;

    char* ws = (char*)d_ws;
    size_t off = 0;
    auto alloc = [&](size_t bytes) { char* p = ws + off; off += (bytes + 255) & ~(size_t)255; return p; };

    __hip_bfloat16* src_b   = (__hip_bfloat16*)alloc((size_t)S_LEN * KDIM_P * 2);
    __hip_bfloat16* projw_b = (__hip_bfloat16*)alloc((size_t)DIM * 5 * KDIM_P * 2);
    __hip_bfloat16* qw_b    = (__hip_bfloat16*)alloc((size_t)DIM * DIM * 2);
    __hip_bfloat16* kvw_b   = (__hip_bfloat16*)alloc((size_t)KV_LD * KDIM_P * 2);
    __hip_bfloat16* outw_b  = (__hip_bfloat16*)alloc((size_t)DIM * DIM * 2);
    __hip_bfloat16* skipw_b = (__hip_bfloat16*)alloc((size_t)DIM * DIM * 2);
    __hip_bfloat16* convwt  = (__hip_bfloat16*)alloc((size_t)NLAYERS * DIM * CONV_K * 2);
    __hip_bfloat16* tgt_b   = (__hip_bfloat16*)alloc((size_t)L_LEN * DIM * 2);
    __hip_bfloat16* q_b     = (__hip_bfloat16*)alloc((size_t)L_LEN * DIM * 2);
    __hip_bfloat16* kv_b    = (__hip_bfloat16*)alloc((size_t)(S_LEN + S_PAD) * KV_LD * 2);
    __hip_bfloat16* o_b     = (__hip_bfloat16*)alloc((size_t)L_LEN * DIM * 2);
    float*          attn_f  = (float*)alloc((size_t)L_LEN * DIM * 4);
    __hip_bfloat16* hp0     = (__hip_bfloat16*)alloc((size_t)(L_LEN + 2) * DIM * 2);
    __hip_bfloat16* hp1     = (__hip_bfloat16*)alloc((size_t)(L_LEN + 2) * DIM * 2);
    float*          conv_f  = (float*)alloc((size_t)L_LEN * DIM * 4);
    float*          skip_f  = attn_f;   // alias: attn_out dead after LN
    (void)ws_size; (void)n_in; (void)in_sizes; (void)out_size;

    // --- staging ---
    build_src_kernel<<<(S_LEN * KDIM_P + 255) / 256, 256, 0, stream>>>(x, src_b);
    convert_pad_kernel<<<(DIM * 5 * KDIM_P + 255) / 256, 256, 0, stream>>>(proj_w, projw_b, DIM * 5, KDIM, KDIM_P);
    convert_pad_kernel<<<(DIM * DIM + 255) / 256, 256, 0, stream>>>(q_w, qw_b, DIM, DIM, DIM);
    convert_pad_kernel<<<(DIM * KDIM_P + 255) / 256, 256, 0, stream>>>(k_w, kvw_b, DIM, KDIM, KDIM_P);
    convert_pad_kernel<<<(DIM * KDIM_P + 255) / 256, 256, 0, stream>>>(v_w, kvw_b + (size_t)DIM * KDIM_P, DIM, KDIM, KDIM_P);
    convert_pad_kernel<<<(DIM * DIM + 255) / 256, 256, 0, stream>>>(out_w, outw_b, DIM, DIM, DIM);
    convert_pad_kernel<<<(DIM * DIM + 255) / 256, 256, 0, stream>>>(skip_w, skipw_b, DIM, DIM, DIM);
    conv_wt_kernel<<<(NLAYERS * DIM * CONV_K + 255) / 256, 256, 0, stream>>>(conv_w, convwt);
    zero_pad_rows_kernel<<<4, 512, 0, stream>>>(hp0, hp1);
    zero_kv_pad_kernel<<<(S_PAD * KV_LD + 255) / 256, 256, 0, stream>>>(kv_b);

    // --- proj: [2048,192] x [2560,192]^T (NK=3) -> tgt [10240,512] ---
    gemm_bk64<false, true><<<dim3(S_LEN / 128, DIM * 5 / 64), 256, 0, stream>>>(
        src_b, KDIM_P, projw_b, KDIM_P, proj_b, tgt_b, nullptr, DIM * 5, KDIM_P);
    // --- q (NK=8) ---
    gemm_bk64<false, true><<<dim3(L_LEN / 128, DIM / 64), 256, 0, stream>>>(
        tgt_b, DIM, qw_b, DIM, in_b, q_b, nullptr, DIM, DIM);
    // --- fused k|v: [2048,192] x [1024,192]^T -> kv_b [2048,1024] (NK=3) ---
    gemm_bk64<false, true><<<dim3(S_LEN / 128, KV_LD / 64), 256, 0, stream>>>(
        src_b, KDIM_P, kvw_b, KDIM_P, in_b + DIM, kv_b, nullptr, KV_LD, KDIM_P);

    // --- banded MFMA attention ---
    attn_mfma_kernel<<<L_LEN / 16, 256, 0, stream>>>(q_b, kv_b, kv_b + DIM, o_b);

    // --- out proj -> f32 (NK=8) ---
    gemm_bk64<false, false><<<dim3(L_LEN / 128, DIM / 64), 256, 0, stream>>>(
        o_b, DIM, outw_b, DIM, out_b, nullptr, attn_f, DIM, DIM);

    // --- LN + residual -> hp0 rows 1..L (bf16) ---
    ln_residual_kernel<<<L_LEN, 256, 0, stream>>>(attn_f, residual, hp0);

    // --- skip GEMM (NK=8) ---
    gemm_bk64<false, false><<<dim3(L_LEN / 128, DIM / 64), 256, 0, stream>>>(
        hp0 + DIM, DIM, skipw_b, DIM, skip_b, nullptr, skip_f, DIM, DIM);

    // --- conv stack: sliding-window GEMMs, K=1536 (NK=24), lda=512 ---
    gemm_bk64<true, true><<<dim3(L_LEN / 128, DIM / 64), 256, 0, stream>>>(
        hp0, DIM, convwt, CONV_K, conv_b, hp1 + DIM, nullptr, DIM, CONV_K);
    gemm_bk64<true, true><<<dim3(L_LEN / 128, DIM / 64), 256, 0, stream>>>(
        hp1, DIM, convwt + (size_t)DIM * CONV_K, CONV_K, conv_b + DIM, hp0 + DIM, nullptr, DIM, CONV_K);
    gemm_bk64<true, false><<<dim3(L_LEN / 128, DIM / 64), 256, 0, stream>>>(
        hp0, DIM, convwt + (size_t)2 * DIM * CONV_K, CONV_K, conv_b + 2 * DIM, nullptr, conv_f, DIM, CONV_K);

    // --- final LN ---
    final_ln_kernel<<<L_LEN, 256, 0, stream>>>(conv_f, skip_f, out);
}

// Round 9
// 295.840 us; speedup vs baseline: 1.3833x; 1.0074x over previous
//
#include <hip/hip_runtime.h>
#include <hip/hip_bf16.h>

// ---------------------------------------------------------------------------
// DecoderBlock: proj -> banded MHA -> LN+residual -> 3x conv1d(softplus) -> LN
// S=2048, L=5S=10240, DIM=512, HEADS=4, hd=128, KDIM=136 (pad->192), EXT=64
// R9: algebraic fusion — q is computed directly from src via pre-composed
// weights Wq5 = qw @ projw_j (tgt never materialized); q|k|v = ONE GEMM
// [2048 x 3584 x 192] with reshape epilogue. All staging in one kernel.
// GEMM core: 128x64 tile, BK=64, dbuf LDS + coalesced LDS epilogue (R8).
// ---------------------------------------------------------------------------

#define S_LEN   2048
#define S_PAD   32
#define L_LEN   10240
#define DIM     512
#define KDIM    136
#define KDIM_P  192
#define HEADS   4
#define HDIM    128
#define NLAYERS 3
#define CONV_K  1536
#define KV_LD   1024     // fused k|v row stride
#define CS_LD   68       // f32 epilogue staging stride
#define NQKV    3584     // 2560 (q5) + 1024 (k|v)

typedef __attribute__((ext_vector_type(8))) short bf16x8;
typedef __attribute__((ext_vector_type(4))) float f32x4;

__device__ __forceinline__ float softplus_f(float x) {
    if (x > 15.0f) return x;
    return __logf(1.0f + __expf(x));
}

__device__ __forceinline__ void gload_lds16(const __hip_bfloat16* g,
                                            __hip_bfloat16* l) {
    __builtin_amdgcn_global_load_lds(
        (const __attribute__((address_space(1))) void*)g,
        (__attribute__((address_space(3))) void*)l, 16, 0, 0);
}

// ---------------------------------------------------------------------------
// GEMM: C[m,n] = act( sum_k A[m*lda+k] * W[n*ldw+k] + bias[n] )
// Block 128x64, 4 waves 2x2 (wave 64x32, 4x2 MFMA), BK=64, dbuf LDS 48KB,
// LDS-staged coalesced epilogue. blockIdx.z batching via az/wz/cz strides.
// QKV: bf16 output routed to qdst (reshape-5) for n<2560 else kvdst.
// ---------------------------------------------------------------------------
template<bool SOFTPLUS, bool OUT_BF16, bool QKV>
__global__ __launch_bounds__(256) void gemm_bk64(
    const __hip_bfloat16* __restrict__ A, int lda,
    const __hip_bfloat16* __restrict__ W, int ldw,
    const float* __restrict__ bias,
    __hip_bfloat16* __restrict__ Cb, float* __restrict__ Cf, int ldc,
    int K, long az, long wz, long cz,
    __hip_bfloat16* __restrict__ qdst, __hip_bfloat16* __restrict__ kvdst)
{
    __shared__ __align__(16) char smem[49152];
    __hip_bfloat16* As = (__hip_bfloat16*)smem;              // 32 KB
    __hip_bfloat16* Bs = (__hip_bfloat16*)(smem + 32768);    // 16 KB
    float*          Cs = (float*)smem;                       // reused epilogue

    A  += (size_t)blockIdx.z * az;
    W  += (size_t)blockIdx.z * wz;
    if (OUT_BF16) Cb += (size_t)blockIdx.z * cz;

    const int t = threadIdx.x;
    const int w = t >> 6;
    const int lane = t & 63;
    const int r16 = lane & 15;
    const int quad = lane >> 4;

    const int m0 = blockIdx.x * 128;
    const int n0 = blockIdx.y * 64;
    const int mo = (w >> 1) * 64;
    const int no = (w & 1) * 32;

    const int srow = w * 16 + (lane >> 2);
    const int scol = (lane & 3) * 8;
    const __hip_bfloat16* Ag0 = A + (size_t)(m0 + srow) * lda + scol;
    const __hip_bfloat16* Ag1 = A + (size_t)(m0 + 64 + srow) * lda + scol;
    const __hip_bfloat16* Wg  = W + (size_t)(n0 + srow) * ldw + scol;
    __hip_bfloat16* lA0 = &As[(size_t)(w * 16) * 32];
    __hip_bfloat16* lA1 = &As[(size_t)(64 + w * 16) * 32];
    __hip_bfloat16* lB  = &Bs[(size_t)(w * 16) * 32];

    f32x4 acc[4][2];
    #pragma unroll
    for (int i = 0; i < 4; ++i)
        #pragma unroll
        for (int j = 0; j < 2; ++j)
            acc[i][j] = (f32x4){0.f, 0.f, 0.f, 0.f};

    const int NK = K >> 6;

    auto stage = [&](int buf, int k0) {
        #pragma unroll
        for (int kh = 0; kh < 2; ++kh) {
            const int gk = k0 + kh * 32;
            gload_lds16(Ag0 + gk, lA0 + buf * 8192 + kh * 4096);
            gload_lds16(Ag1 + gk, lA1 + buf * 8192 + kh * 4096);
            gload_lds16(Wg  + gk, lB  + buf * 4096 + kh * 2048);
        }
    };

    stage(0, 0);

    for (int k = 0; k < NK; ++k) {
        const int buf = k & 1;
        if (k + 1 < NK) {
            stage(buf ^ 1, (k + 1) << 6);
            asm volatile("s_waitcnt vmcnt(6)" ::: "memory");
        } else {
            asm volatile("s_waitcnt vmcnt(0)" ::: "memory");
        }
        asm volatile("s_barrier" ::: "memory");

        #pragma unroll
        for (int kh = 0; kh < 2; ++kh) {
            const __hip_bfloat16* Asb = As + buf * 8192 + kh * 4096;
            const __hip_bfloat16* Bsb = Bs + buf * 4096 + kh * 2048;
            bf16x8 af[4], bfr[2];
            #pragma unroll
            for (int i = 0; i < 4; ++i)
                af[i] = *(const bf16x8*)&Asb[(mo + i * 16 + r16) * 32 + quad * 8];
            #pragma unroll
            for (int j = 0; j < 2; ++j)
                bfr[j] = *(const bf16x8*)&Bsb[(no + j * 16 + r16) * 32 + quad * 8];
            #pragma unroll
            for (int i = 0; i < 4; ++i)
                #pragma unroll
                for (int j = 0; j < 2; ++j)
                    acc[i][j] = __builtin_amdgcn_mfma_f32_16x16x32_bf16(
                        af[i], bfr[j], acc[i][j], 0, 0, 0);
        }

        asm volatile("s_waitcnt lgkmcnt(0)" ::: "memory");
        asm volatile("s_barrier" ::: "memory");
    }

    // ---- epilogue: acc -> Cs (f32, bias+act applied) ----
    #pragma unroll
    for (int i = 0; i < 4; ++i) {
        const int rl = mo + i * 16 + quad * 4;
        #pragma unroll
        for (int j = 0; j < 2; ++j) {
            const int cl = no + j * 16 + r16;
            const float bs = bias[n0 + cl];
            #pragma unroll
            for (int r = 0; r < 4; ++r) {
                float v = acc[i][j][r] + bs;
                if (SOFTPLUS) v = softplus_f(v);
                Cs[(rl + r) * CS_LD + cl] = v;
            }
        }
    }
    __syncthreads();

    // ---- coalesced stores ----
    if (OUT_BF16) {
        const int rsub = lane >> 3;
        const int c8 = (lane & 7) * 8;
        __hip_bfloat16* base;
        long rstride;
        if (QKV) {
            if (n0 < 2560) { base = qdst + n0;          rstride = 2560; }
            else           { base = kvdst + (n0 - 2560); rstride = KV_LD; }
        } else {
            base = Cb + n0; rstride = ldc;
        }
        #pragma unroll
        for (int it = 0; it < 4; ++it) {
            const int rl = w * 32 + it * 8 + rsub;
            const float* src = &Cs[rl * CS_LD + c8];
            f32x4 a = *(const f32x4*)src;
            f32x4 b = *(const f32x4*)(src + 4);
            bf16x8 o;
            #pragma unroll
            for (int e = 0; e < 4; ++e) {
                __hip_bfloat16 x = __float2bfloat16(a[e]);
                __hip_bfloat16 y = __float2bfloat16(b[e]);
                o[e]     = *(short*)&x;
                o[e + 4] = *(short*)&y;
            }
            *(bf16x8*)(base + (size_t)(m0 + rl) * rstride + c8) = o;
        }
    } else {
        const int rsub = lane >> 4;
        const int c4 = (lane & 15) * 4;
        #pragma unroll
        for (int it = 0; it < 8; ++it) {
            const int rl = w * 32 + it * 4 + rsub;
            f32x4 a = *(const f32x4*)&Cs[rl * CS_LD + c4];
            *(f32x4*)(Cf + (size_t)(m0 + rl) * ldc + n0 + c4) = a;
        }
    }
}

// ---------------------------------------------------------------------------
// Banded MFMA attention (unchanged from R8).
// ---------------------------------------------------------------------------
#define VT_STRIDE 40

__global__ __launch_bounds__(256) void attn_mfma_kernel(
    const __hip_bfloat16* __restrict__ qb,
    const __hip_bfloat16* __restrict__ kb,
    const __hip_bfloat16* __restrict__ vb,
    __hip_bfloat16* __restrict__ ob)
{
    __shared__ __hip_bfloat16 Vt[HEADS][HDIM * VT_STRIDE];
    __shared__ __hip_bfloat16 Ps[HEADS][16 * 32];

    const int t = threadIdx.x;
    const int h = t >> 6;
    const int lane = t & 63;
    const int r16 = lane & 15;
    const int quad = lane >> 4;
    const int l0 = blockIdx.x * 16;

    int i_start = (l0 - 64) / 5;
    if (i_start < 0) i_start = 0;

    {
        const int s = lane & 31;
        const int half = lane >> 5;
        const __hip_bfloat16* vrow =
            vb + (size_t)(i_start + s) * KV_LD + h * HDIM + half * 64;
        short* vt = (short*)Vt[h];
        #pragma unroll
        for (int jj = 0; jj < 8; ++jj) {
            bf16x8 v = *(const bf16x8*)(vrow + jj * 8);
            #pragma unroll
            for (int e = 0; e < 8; ++e)
                vt[(half * 64 + jj * 8 + e) * VT_STRIDE + s] = v[e];
        }
    }

    const short* qg = (const short*)qb + (size_t)(l0 + r16) * DIM + h * HDIM + quad * 8;
    const short* kg0 = (const short*)kb + (size_t)(i_start + r16) * KV_LD + h * HDIM + quad * 8;
    const short* kg1 = kg0 + 16 * KV_LD;

    f32x4 c0 = {0.f, 0.f, 0.f, 0.f};
    f32x4 c1 = {0.f, 0.f, 0.f, 0.f};
    #pragma unroll
    for (int kk = 0; kk < 4; ++kk) {
        bf16x8 aq = *(const bf16x8*)(qg + kk * 32);
        bf16x8 b0 = *(const bf16x8*)(kg0 + kk * 32);
        bf16x8 b1 = *(const bf16x8*)(kg1 + kk * 32);
        c0 = __builtin_amdgcn_mfma_f32_16x16x32_bf16(aq, b0, c0, 0, 0, 0);
        c1 = __builtin_amdgcn_mfma_f32_16x16x32_bf16(aq, b1, c1, 0, 0, 0);
    }

    const float scale = 0.08838834764831845f;
    const int ic0 = i_start + r16;
    const int ic1 = ic0 + 16;
    float recl[4];
    short* ps = (short*)Ps[h];
    #pragma unroll
    for (int r = 0; r < 4; ++r) {
        const int l = l0 + quad * 4 + r;
        const bool a0 = (l >= 5 * ic0 - 64) && (l < 5 * ic0 + 69) && (ic0 < S_LEN);
        const bool a1 = (l >= 5 * ic1 - 64) && (l < 5 * ic1 + 69) && (ic1 < S_LEN);
        float s0 = a0 ? c0[r] * scale : -1e30f;
        float s1 = a1 ? c1[r] * scale : -1e30f;
        float mx = fmaxf(s0, s1);
        #pragma unroll
        for (int o = 8; o; o >>= 1) mx = fmaxf(mx, __shfl_xor(mx, o));
        float e0 = __expf(s0 - mx);
        float e1 = __expf(s1 - mx);
        float sm = e0 + e1;
        #pragma unroll
        for (int o = 8; o; o >>= 1) sm += __shfl_xor(sm, o);
        recl[r] = 1.0f / sm;
        __hip_bfloat16 p0 = __float2bfloat16(e0);
        __hip_bfloat16 p1 = __float2bfloat16(e1);
        ps[(quad * 4 + r) * 32 + r16]      = *(short*)&p0;
        ps[(quad * 4 + r) * 32 + r16 + 16] = *(short*)&p1;
    }

    __syncthreads();

    bf16x8 ap = *(const bf16x8*)&Ps[h][r16 * 32 + quad * 8];
    #pragma unroll
    for (int nt = 0; nt < 8; ++nt) {
        bf16x8 bv = *(const bf16x8*)&Vt[h][(nt * 16 + r16) * VT_STRIDE + quad * 8];
        f32x4 o = {0.f, 0.f, 0.f, 0.f};
        o = __builtin_amdgcn_mfma_f32_16x16x32_bf16(ap, bv, o, 0, 0, 0);
        #pragma unroll
        for (int r = 0; r < 4; ++r) {
            ob[(size_t)(l0 + quad * 4 + r) * DIM + h * HDIM + nt * 16 + r16] =
                __float2bfloat16(o[r] * recl[r]);
        }
    }
}

// ---------------------------------------------------------------------------
// LayerNorm kernels (unchanged)
// ---------------------------------------------------------------------------
__global__ __launch_bounds__(256) void ln_residual_kernel(
    const float* __restrict__ attn_out, const float* __restrict__ residual,
    __hip_bfloat16* __restrict__ hp0)
{
    __shared__ float red[4];
    const int r = blockIdx.x;
    const int t = threadIdx.x;
    const size_t base = (size_t)r * DIM + t * 2;
    float z0 = attn_out[base], z1 = attn_out[base + 1];

    float s = z0 + z1;
    #pragma unroll
    for (int o = 32; o; o >>= 1) s += __shfl_xor(s, o);
    if ((t & 63) == 0) red[t >> 6] = s;
    __syncthreads();
    const float mean = (red[0] + red[1] + red[2] + red[3]) * (1.0f / DIM);
    __syncthreads();

    const float d0 = z0 - mean, d1 = z1 - mean;
    float vq = d0 * d0 + d1 * d1;
    #pragma unroll
    for (int o = 32; o; o >>= 1) vq += __shfl_xor(vq, o);
    if ((t & 63) == 0) red[t >> 6] = vq;
    __syncthreads();
    const float var = (red[0] + red[1] + red[2] + red[3]) * (1.0f / DIM);
    const float rstd = rsqrtf(var + 1e-5f);

    const float y0 = d0 * rstd + residual[base];
    const float y1 = d1 * rstd + residual[base + 1];
    __hip_bfloat16* out = hp0 + (size_t)(r + 1) * DIM + t * 2;
    out[0] = __float2bfloat16(y0);
    out[1] = __float2bfloat16(y1);
}

__global__ __launch_bounds__(256) void final_ln_kernel(
    const float* __restrict__ conv_out, const float* __restrict__ skip_out,
    float* __restrict__ out)
{
    __shared__ float red[4];
    const int r = blockIdx.x;
    const int t = threadIdx.x;
    const size_t base = (size_t)r * DIM + t * 2;
    float z0 = conv_out[base] + skip_out[base];
    float z1 = conv_out[base + 1] + skip_out[base + 1];

    float s = z0 + z1;
    #pragma unroll
    for (int o = 32; o; o >>= 1) s += __shfl_xor(s, o);
    if ((t & 63) == 0) red[t >> 6] = s;
    __syncthreads();
    const float mean = (red[0] + red[1] + red[2] + red[3]) * (1.0f / DIM);
    __syncthreads();

    const float d0 = z0 - mean, d1 = z1 - mean;
    float vq = d0 * d0 + d1 * d1;
    #pragma unroll
    for (int o = 32; o; o >>= 1) vq += __shfl_xor(vq, o);
    if ((t & 63) == 0) red[t >> 6] = vq;
    __syncthreads();
    const float var = (red[0] + red[1] + red[2] + red[3]) * (1.0f / DIM);
    const float rstd = rsqrtf(var + 1e-5f);

    out[base]     = d0 * rstd;
    out[base + 1] = d1 * rstd;
}

// ---------------------------------------------------------------------------
// One merged staging kernel: src build, projw^T, qw, k|v weights, outw,
// skipw, convwt, kv pad rows, hp pad rows, zeros.
// ---------------------------------------------------------------------------
#define SG0 (S_LEN * KDIM_P)        // src_b
#define SG1 (5 * KDIM_P * DIM)      // projw_T [5][KDIM_P][512]
#define SG2 (DIM * DIM)             // qw_b
#define SG3 (KV_LD * KDIM_P)        // k|v weights -> W_all rows 2560..3583
#define SG4 (DIM * DIM)             // outw_b
#define SG5 (DIM * DIM)             // skipw_b
#define SG6 (NLAYERS * DIM * CONV_K)// convwt
#define SG7 (S_PAD * KV_LD)         // kv pad rows
#define SG8 (4 * DIM)               // hp pad rows
#define SG9 (4096)                  // zeros (f32)
#define SG_TOTAL (SG0+SG1+SG2+SG3+SG4+SG5+SG6+SG7+SG8+SG9)

__global__ void stage_all_kernel(
    const float* __restrict__ x, const float* __restrict__ proj_w,
    const float* __restrict__ q_w, const float* __restrict__ k_w,
    const float* __restrict__ v_w, const float* __restrict__ out_w,
    const float* __restrict__ skip_w, const float* __restrict__ conv_w,
    __hip_bfloat16* src_b, __hip_bfloat16* projw_T, __hip_bfloat16* qw_b,
    __hip_bfloat16* W_all, __hip_bfloat16* outw_b, __hip_bfloat16* skipw_b,
    __hip_bfloat16* convwt, __hip_bfloat16* kv_b,
    __hip_bfloat16* hp0, __hip_bfloat16* hp1, float* zeros)
{
    int idx = blockIdx.x * 256 + threadIdx.x;
    if (idx >= SG_TOTAL) return;
    const __hip_bfloat16 zb = __float2bfloat16(0.f);

    if (idx < SG0) {                       // src: [S][KDIM_P], x + pos emb
        int i = idx / KDIM_P, j = idx % KDIM_P;
        float v;
        if (j < 128)       v = x[i * 128 + j];
        else if (j < KDIM) { int e = j - 128; v = (float)(i & ((2 << e) - 1)) / (float)(1 << e); }
        else               v = 0.f;
        src_b[idx] = __float2bfloat16(v);
        return;
    }
    idx -= SG0;
    if (idx < SG1) {                       // projw_T[j][k][d] = proj_w[(j*512+d)*KDIM + k]
        int j = idx / (KDIM_P * DIM);
        int rem = idx % (KDIM_P * DIM);
        int k = rem / DIM, d = rem % DIM;
        projw_T[idx] = (k < KDIM)
            ? __float2bfloat16(proj_w[(size_t)(j * DIM + d) * KDIM + k]) : zb;
        return;
    }
    idx -= SG1;
    if (idx < SG2) { qw_b[idx] = __float2bfloat16(q_w[idx]); return; }
    idx -= SG2;
    if (idx < SG3) {                       // W_all rows 2560+: k then v
        int r = idx / KDIM_P, c = idx % KDIM_P;
        float v = 0.f;
        if (c < KDIM) v = (r < DIM) ? k_w[(size_t)r * KDIM + c]
                                    : v_w[(size_t)(r - DIM) * KDIM + c];
        W_all[(size_t)(2560 + r) * KDIM_P + c] = __float2bfloat16(v);
        return;
    }
    idx -= SG3;
    if (idx < SG4) { outw_b[idx] = __float2bfloat16(out_w[idx]); return; }
    idx -= SG4;
    if (idx < SG5) { skipw_b[idx] = __float2bfloat16(skip_w[idx]); return; }
    idx -= SG5;
    if (idx < SG6) {                       // convwt [3][512][3*512] as [c][k][ci]
        int lc = idx / CONV_K;
        int rem = idx % CONV_K;
        int k = rem / DIM, ci = rem % DIM;
        convwt[idx] = __float2bfloat16(conv_w[(size_t)lc * CONV_K + ci * 3 + k]);
        return;
    }
    idx -= SG6;
    if (idx < SG7) { kv_b[(size_t)S_LEN * KV_LD + idx] = zb; return; }
    idx -= SG7;
    if (idx < SG8) {                       // hp pad rows
        int t = idx % DIM, which = idx / DIM;
        if      (which == 0) hp0[t] = zb;
        else if (which == 1) hp0[(size_t)(L_LEN + 1) * DIM + t] = zb;
        else if (which == 2) hp1[t] = zb;
        else                 hp1[(size_t)(L_LEN + 1) * DIM + t] = zb;
        return;
    }
    idx -= SG8;
    zeros[idx] = 0.f;
}

// bias_all[n], n<2560: qw @ proj_b_j + in_b[:512]; n>=2560: in_b[512+...]
__global__ void bias_all_kernel(const float* __restrict__ q_w,
                                const float* __restrict__ proj_b,
                                const float* __restrict__ in_b,
                                float* __restrict__ bias_all)
{
    int n = blockIdx.x * 256 + threadIdx.x;
    if (n >= NQKV) return;
    if (n < 2560) {
        int j = n / DIM, c = n % DIM;
        float s = in_b[c];
        for (int d = 0; d < DIM; ++d)
            s += q_w[(size_t)c * DIM + d] * proj_b[j * DIM + d];
        bias_all[n] = s;
    } else {
        bias_all[n] = in_b[DIM + (n - 2560)];
    }
}

// ---------------------------------------------------------------------------
extern "C" void kernel_launch(void* const* d_in, const int* in_sizes, int n_in,
                              void* d_out, int out_size, void* d_ws, size_t ws_size,
                              hipStream_t stream)
{
    const float* x        = (const float*)d_in[0];
    const float* residual = (const float*)d_in[1];
    const float* proj_w   = (const float*)d_in[2];
    const float* proj_b   = (const float*)d_in[3];
    const float* q_w      = (const float*)d_in[4];
    const float* k_w      = (const float*)d_in[5];
    const float* v_w      = (const float*)d_in[6];
    const float* in_b     = (const float*)d_in[7];
    const float* out_w    = (const float*)d_in[8];
    const float* out_b    = (const float*)d_in[9];
    const float* conv_w   = (const float*)d_in[10];
    const float* conv_b   = (const float*)d_in[11];
    const float* skip_w   = (const float*)d_in[12];
    const float* skip_b   = (const float*)d_in[13];
    float* out = (float*)d_out;

    char* ws = (char*)d_ws;
    size_t off = 0;
    auto alloc = [&](size_t bytes) { char* p = ws + off; off += (bytes + 255) & ~(size_t)255; return p; };

    __hip_bfloat16* src_b   = (__hip_bfloat16*)alloc((size_t)S_LEN * KDIM_P * 2);
    __hip_bfloat16* projw_T = (__hip_bfloat16*)alloc((size_t)5 * KDIM_P * DIM * 2);
    __hip_bfloat16* qw_b    = (__hip_bfloat16*)alloc((size_t)DIM * DIM * 2);
    __hip_bfloat16* W_all   = (__hip_bfloat16*)alloc((size_t)NQKV * KDIM_P * 2);
    __hip_bfloat16* outw_b  = (__hip_bfloat16*)alloc((size_t)DIM * DIM * 2);
    __hip_bfloat16* skipw_b = (__hip_bfloat16*)alloc((size_t)DIM * DIM * 2);
    __hip_bfloat16* convwt  = (__hip_bfloat16*)alloc((size_t)NLAYERS * DIM * CONV_K * 2);
    float*          zeros   = (float*)alloc(4096 * 4);
    float*          bias_qkv= (float*)alloc(NQKV * 4);
    __hip_bfloat16* q_b     = (__hip_bfloat16*)alloc((size_t)L_LEN * DIM * 2);
    __hip_bfloat16* kv_b    = (__hip_bfloat16*)alloc((size_t)(S_LEN + S_PAD) * KV_LD * 2);
    __hip_bfloat16* o_b     = (__hip_bfloat16*)alloc((size_t)L_LEN * DIM * 2);
    float*          attn_f  = (float*)alloc((size_t)L_LEN * DIM * 4);
    __hip_bfloat16* hp0     = (__hip_bfloat16*)alloc((size_t)(L_LEN + 2) * DIM * 2);
    __hip_bfloat16* hp1     = (__hip_bfloat16*)alloc((size_t)(L_LEN + 2) * DIM * 2);
    float*          conv_f  = (float*)alloc((size_t)L_LEN * DIM * 4);
    float*          skip_f  = attn_f;   // alias: attn_out dead after LN
    (void)ws_size; (void)n_in; (void)in_sizes; (void)out_size;

    // --- staging (1 dispatch) + bias precompute ---
    stage_all_kernel<<<(SG_TOTAL + 255) / 256, 256, 0, stream>>>(
        x, proj_w, q_w, k_w, v_w, out_w, skip_w, conv_w,
        src_b, projw_T, qw_b, W_all, outw_b, skipw_b, convwt, kv_b,
        hp0, hp1, zeros);
    bias_all_kernel<<<(NQKV + 255) / 256, 256, 0, stream>>>(
        q_w, proj_b, in_b, bias_qkv);

    // --- Wq5_j = qw @ projw_j : [512, KDIM_P] x5 -> W_all rows 0..2559 ---
    gemm_bk64<false, true, false><<<dim3(4, KDIM_P / 64, 5), 256, 0, stream>>>(
        qw_b, DIM, projw_T, DIM, zeros, W_all, nullptr, KDIM_P, DIM,
        0, (long)KDIM_P * DIM, (long)DIM * KDIM_P, nullptr, nullptr);

    // --- fused QKV: src [2048,192] x W_all [3584,192]^T, reshape epilogue ---
    gemm_bk64<false, true, true><<<dim3(S_LEN / 128, NQKV / 64), 256, 0, stream>>>(
        src_b, KDIM_P, W_all, KDIM_P, bias_qkv, nullptr, nullptr, 0, KDIM_P,
        0, 0, 0, q_b, kv_b);

    // --- banded MFMA attention ---
    attn_mfma_kernel<<<L_LEN / 16, 256, 0, stream>>>(q_b, kv_b, kv_b + DIM, o_b);

    // --- out proj -> f32 ---
    gemm_bk64<false, false, false><<<dim3(L_LEN / 128, DIM / 64), 256, 0, stream>>>(
        o_b, DIM, outw_b, DIM, out_b, nullptr, attn_f, DIM, DIM,
        0, 0, 0, nullptr, nullptr);

    // --- LN + residual -> hp0 rows 1..L (bf16) ---
    ln_residual_kernel<<<L_LEN, 256, 0, stream>>>(attn_f, residual, hp0);

    // --- skip GEMM ---
    gemm_bk64<false, false, false><<<dim3(L_LEN / 128, DIM / 64), 256, 0, stream>>>(
        hp0 + DIM, DIM, skipw_b, DIM, skip_b, nullptr, skip_f, DIM, DIM,
        0, 0, 0, nullptr, nullptr);

    // --- conv stack: sliding-window GEMMs, K=1536 ---
    gemm_bk64<true, true, false><<<dim3(L_LEN / 128, DIM / 64), 256, 0, stream>>>(
        hp0, DIM, convwt, CONV_K, conv_b, hp1 + DIM, nullptr, DIM, CONV_K,
        0, 0, 0, nullptr, nullptr);
    gemm_bk64<true, true, false><<<dim3(L_LEN / 128, DIM / 64), 256, 0, stream>>>(
        hp1, DIM, convwt + (size_t)DIM * CONV_K, CONV_K, conv_b + DIM, hp0 + DIM, nullptr, DIM, CONV_K,
        0, 0, 0, nullptr, nullptr);
    gemm_bk64<true, false, false><<<dim3(L_LEN / 128, DIM / 64), 256, 0, stream>>>(
        hp0, DIM, convwt + (size_t)2 * DIM * CONV_K, CONV_K, conv_b + 2 * DIM, nullptr, conv_f, DIM, CONV_K,
        0, 0, 0, nullptr, nullptr);

    // --- final LN ---
    final_ln_kernel<<<L_LEN, 256, 0, stream>>>(conv_f, skip_f, out);
}

// Round 10
// 275.020 us; speedup vs baseline: 1.4880x; 1.0757x over previous
//
#include <hip/hip_runtime.h>
#include <hip/hip_bf16.h>

// ---------------------------------------------------------------------------
// DecoderBlock: proj -> banded MHA -> LN+residual -> 3x conv1d(softplus) -> LN
// R10: (1) XOR-swizzled LDS layout for GEMM fragments — kills the 8-way
// ds_read_b128 bank conflict (2.95M/dispatch -> ~0). Source-side permute via
// per-lane global addresses; DMA dest (base+lane*16) untouched.
// (2) wave-parallel bias_all (was a 512-serial loop on 14 blocks).
// GEMM core: 128x64 tile, BK=64, dbuf LDS + coalesced LDS epilogue.
// ---------------------------------------------------------------------------

#define S_LEN   2048
#define S_PAD   32
#define L_LEN   10240
#define DIM     512
#define KDIM    136
#define KDIM_P  192
#define HEADS   4
#define HDIM    128
#define NLAYERS 3
#define CONV_K  1536
#define KV_LD   1024     // fused k|v row stride
#define CS_LD   68       // f32 epilogue staging stride
#define NQKV    3584     // 2560 (q5) + 1024 (k|v)

typedef __attribute__((ext_vector_type(8))) short bf16x8;
typedef __attribute__((ext_vector_type(4))) float f32x4;

__device__ __forceinline__ float softplus_f(float x) {
    if (x > 15.0f) return x;
    return __logf(1.0f + __expf(x));
}

__device__ __forceinline__ void gload_lds16(const __hip_bfloat16* g,
                                            __hip_bfloat16* l) {
    __builtin_amdgcn_global_load_lds(
        (const __attribute__((address_space(1))) void*)g,
        (__attribute__((address_space(3))) void*)l, 16, 0, 0);
}

// ---------------------------------------------------------------------------
// GEMM: C[m,n] = act( sum_k A[m*lda+k] * W[n*ldw+k] + bias[n] )
// Block 128x64, 4 waves 2x2 (wave 64x32, 4x2 MFMA), BK=64, dbuf LDS 48KB.
// LDS layout swizzle: within each 16-row DMA group, row r stores global
// k-block kb at slot (kb + (r>>1)) & 3  ->  frag reads are 2-way (free).
// QKV template: bf16 output routed to qdst (reshape-5) / kvdst.
// ---------------------------------------------------------------------------
template<bool SOFTPLUS, bool OUT_BF16, bool QKV>
__global__ __launch_bounds__(256) void gemm_bk64(
    const __hip_bfloat16* __restrict__ A, int lda,
    const __hip_bfloat16* __restrict__ W, int ldw,
    const float* __restrict__ bias,
    __hip_bfloat16* __restrict__ Cb, float* __restrict__ Cf, int ldc,
    int K, long az, long wz, long cz,
    __hip_bfloat16* __restrict__ qdst, __hip_bfloat16* __restrict__ kvdst)
{
    __shared__ __align__(16) char smem[49152];
    __hip_bfloat16* As = (__hip_bfloat16*)smem;              // 32 KB
    __hip_bfloat16* Bs = (__hip_bfloat16*)(smem + 32768);    // 16 KB
    float*          Cs = (float*)smem;                       // reused epilogue

    A  += (size_t)blockIdx.z * az;
    W  += (size_t)blockIdx.z * wz;
    if (OUT_BF16) Cb += (size_t)blockIdx.z * cz;

    const int t = threadIdx.x;
    const int w = t >> 6;
    const int lane = t & 63;
    const int r16 = lane & 15;
    const int quad = lane >> 4;

    const int m0 = blockIdx.x * 128;
    const int n0 = blockIdx.y * 64;
    const int mo = (w >> 1) * 64;
    const int no = (w & 1) * 32;

    // staging with swizzled SOURCE k-block: lane -> local row r=lane>>2,
    // LDS slot s=lane&3 receives global kb = (s - (r>>1)) & 3.
    const int r_loc = lane >> 2;
    const int kb    = ((lane & 3) - (r_loc >> 1)) & 3;
    const int srow  = w * 16 + r_loc;
    const int scol  = kb * 8;
    const __hip_bfloat16* Ag0 = A + (size_t)(m0 + srow) * lda + scol;
    const __hip_bfloat16* Ag1 = A + (size_t)(m0 + 64 + srow) * lda + scol;
    const __hip_bfloat16* Wg  = W + (size_t)(n0 + srow) * ldw + scol;
    __hip_bfloat16* lA0 = &As[(size_t)(w * 16) * 32];
    __hip_bfloat16* lA1 = &As[(size_t)(64 + w * 16) * 32];
    __hip_bfloat16* lB  = &Bs[(size_t)(w * 16) * 32];

    // swizzled read slot offset for this lane (same for every 16-row group)
    const int rs = ((quad + (r16 >> 1)) & 3) * 8;

    f32x4 acc[4][2];
    #pragma unroll
    for (int i = 0; i < 4; ++i)
        #pragma unroll
        for (int j = 0; j < 2; ++j)
            acc[i][j] = (f32x4){0.f, 0.f, 0.f, 0.f};

    const int NK = K >> 6;

    auto stage = [&](int buf, int k0) {
        #pragma unroll
        for (int kh = 0; kh < 2; ++kh) {
            const int gk = k0 + kh * 32;
            gload_lds16(Ag0 + gk, lA0 + buf * 8192 + kh * 4096);
            gload_lds16(Ag1 + gk, lA1 + buf * 8192 + kh * 4096);
            gload_lds16(Wg  + gk, lB  + buf * 4096 + kh * 2048);
        }
    };

    stage(0, 0);

    for (int k = 0; k < NK; ++k) {
        const int buf = k & 1;
        if (k + 1 < NK) {
            stage(buf ^ 1, (k + 1) << 6);
            asm volatile("s_waitcnt vmcnt(6)" ::: "memory");
        } else {
            asm volatile("s_waitcnt vmcnt(0)" ::: "memory");
        }
        asm volatile("s_barrier" ::: "memory");

        #pragma unroll
        for (int kh = 0; kh < 2; ++kh) {
            const __hip_bfloat16* Asb = As + buf * 8192 + kh * 4096;
            const __hip_bfloat16* Bsb = Bs + buf * 4096 + kh * 2048;
            bf16x8 af[4], bfr[2];
            #pragma unroll
            for (int i = 0; i < 4; ++i)
                af[i] = *(const bf16x8*)&Asb[(mo + i * 16 + r16) * 32 + rs];
            #pragma unroll
            for (int j = 0; j < 2; ++j)
                bfr[j] = *(const bf16x8*)&Bsb[(no + j * 16 + r16) * 32 + rs];
            #pragma unroll
            for (int i = 0; i < 4; ++i)
                #pragma unroll
                for (int j = 0; j < 2; ++j)
                    acc[i][j] = __builtin_amdgcn_mfma_f32_16x16x32_bf16(
                        af[i], bfr[j], acc[i][j], 0, 0, 0);
        }

        asm volatile("s_waitcnt lgkmcnt(0)" ::: "memory");
        asm volatile("s_barrier" ::: "memory");
    }

    // ---- epilogue: acc -> Cs (f32, bias+act applied) ----
    #pragma unroll
    for (int i = 0; i < 4; ++i) {
        const int rl = mo + i * 16 + quad * 4;
        #pragma unroll
        for (int j = 0; j < 2; ++j) {
            const int cl = no + j * 16 + r16;
            const float bs = bias[n0 + cl];
            #pragma unroll
            for (int r = 0; r < 4; ++r) {
                float v = acc[i][j][r] + bs;
                if (SOFTPLUS) v = softplus_f(v);
                Cs[(rl + r) * CS_LD + cl] = v;
            }
        }
    }
    __syncthreads();

    // ---- coalesced stores ----
    if (OUT_BF16) {
        const int rsub = lane >> 3;
        const int c8 = (lane & 7) * 8;
        __hip_bfloat16* base;
        long rstride;
        if (QKV) {
            if (n0 < 2560) { base = qdst + n0;           rstride = 2560; }
            else           { base = kvdst + (n0 - 2560); rstride = KV_LD; }
        } else {
            base = Cb + n0; rstride = ldc;
        }
        #pragma unroll
        for (int it = 0; it < 4; ++it) {
            const int rl = w * 32 + it * 8 + rsub;
            const float* src = &Cs[rl * CS_LD + c8];
            f32x4 a = *(const f32x4*)src;
            f32x4 b = *(const f32x4*)(src + 4);
            bf16x8 o;
            #pragma unroll
            for (int e = 0; e < 4; ++e) {
                __hip_bfloat16 x = __float2bfloat16(a[e]);
                __hip_bfloat16 y = __float2bfloat16(b[e]);
                o[e]     = *(short*)&x;
                o[e + 4] = *(short*)&y;
            }
            *(bf16x8*)(base + (size_t)(m0 + rl) * rstride + c8) = o;
        }
    } else {
        const int rsub = lane >> 4;
        const int c4 = (lane & 15) * 4;
        #pragma unroll
        for (int it = 0; it < 8; ++it) {
            const int rl = w * 32 + it * 4 + rsub;
            f32x4 a = *(const f32x4*)&Cs[rl * CS_LD + c4];
            *(f32x4*)(Cf + (size_t)(m0 + rl) * ldc + n0 + c4) = a;
        }
    }
}

// ---------------------------------------------------------------------------
// Banded MFMA attention (unchanged).
// ---------------------------------------------------------------------------
#define VT_STRIDE 40

__global__ __launch_bounds__(256) void attn_mfma_kernel(
    const __hip_bfloat16* __restrict__ qb,
    const __hip_bfloat16* __restrict__ kb,
    const __hip_bfloat16* __restrict__ vb,
    __hip_bfloat16* __restrict__ ob)
{
    __shared__ __hip_bfloat16 Vt[HEADS][HDIM * VT_STRIDE];
    __shared__ __hip_bfloat16 Ps[HEADS][16 * 32];

    const int t = threadIdx.x;
    const int h = t >> 6;
    const int lane = t & 63;
    const int r16 = lane & 15;
    const int quad = lane >> 4;
    const int l0 = blockIdx.x * 16;

    int i_start = (l0 - 64) / 5;
    if (i_start < 0) i_start = 0;

    {
        const int s = lane & 31;
        const int half = lane >> 5;
        const __hip_bfloat16* vrow =
            vb + (size_t)(i_start + s) * KV_LD + h * HDIM + half * 64;
        short* vt = (short*)Vt[h];
        #pragma unroll
        for (int jj = 0; jj < 8; ++jj) {
            bf16x8 v = *(const bf16x8*)(vrow + jj * 8);
            #pragma unroll
            for (int e = 0; e < 8; ++e)
                vt[(half * 64 + jj * 8 + e) * VT_STRIDE + s] = v[e];
        }
    }

    const short* qg = (const short*)qb + (size_t)(l0 + r16) * DIM + h * HDIM + quad * 8;
    const short* kg0 = (const short*)kb + (size_t)(i_start + r16) * KV_LD + h * HDIM + quad * 8;
    const short* kg1 = kg0 + 16 * KV_LD;

    f32x4 c0 = {0.f, 0.f, 0.f, 0.f};
    f32x4 c1 = {0.f, 0.f, 0.f, 0.f};
    #pragma unroll
    for (int kk = 0; kk < 4; ++kk) {
        bf16x8 aq = *(const bf16x8*)(qg + kk * 32);
        bf16x8 b0 = *(const bf16x8*)(kg0 + kk * 32);
        bf16x8 b1 = *(const bf16x8*)(kg1 + kk * 32);
        c0 = __builtin_amdgcn_mfma_f32_16x16x32_bf16(aq, b0, c0, 0, 0, 0);
        c1 = __builtin_amdgcn_mfma_f32_16x16x32_bf16(aq, b1, c1, 0, 0, 0);
    }

    const float scale = 0.08838834764831845f;
    const int ic0 = i_start + r16;
    const int ic1 = ic0 + 16;
    float recl[4];
    short* ps = (short*)Ps[h];
    #pragma unroll
    for (int r = 0; r < 4; ++r) {
        const int l = l0 + quad * 4 + r;
        const bool a0 = (l >= 5 * ic0 - 64) && (l < 5 * ic0 + 69) && (ic0 < S_LEN);
        const bool a1 = (l >= 5 * ic1 - 64) && (l < 5 * ic1 + 69) && (ic1 < S_LEN);
        float s0 = a0 ? c0[r] * scale : -1e30f;
        float s1 = a1 ? c1[r] * scale : -1e30f;
        float mx = fmaxf(s0, s1);
        #pragma unroll
        for (int o = 8; o; o >>= 1) mx = fmaxf(mx, __shfl_xor(mx, o));
        float e0 = __expf(s0 - mx);
        float e1 = __expf(s1 - mx);
        float sm = e0 + e1;
        #pragma unroll
        for (int o = 8; o; o >>= 1) sm += __shfl_xor(sm, o);
        recl[r] = 1.0f / sm;
        __hip_bfloat16 p0 = __float2bfloat16(e0);
        __hip_bfloat16 p1 = __float2bfloat16(e1);
        ps[(quad * 4 + r) * 32 + r16]      = *(short*)&p0;
        ps[(quad * 4 + r) * 32 + r16 + 16] = *(short*)&p1;
    }

    __syncthreads();

    bf16x8 ap = *(const bf16x8*)&Ps[h][r16 * 32 + quad * 8];
    #pragma unroll
    for (int nt = 0; nt < 8; ++nt) {
        bf16x8 bv = *(const bf16x8*)&Vt[h][(nt * 16 + r16) * VT_STRIDE + quad * 8];
        f32x4 o = {0.f, 0.f, 0.f, 0.f};
        o = __builtin_amdgcn_mfma_f32_16x16x32_bf16(ap, bv, o, 0, 0, 0);
        #pragma unroll
        for (int r = 0; r < 4; ++r) {
            ob[(size_t)(l0 + quad * 4 + r) * DIM + h * HDIM + nt * 16 + r16] =
                __float2bfloat16(o[r] * recl[r]);
        }
    }
}

// ---------------------------------------------------------------------------
// LayerNorm kernels (unchanged)
// ---------------------------------------------------------------------------
__global__ __launch_bounds__(256) void ln_residual_kernel(
    const float* __restrict__ attn_out, const float* __restrict__ residual,
    __hip_bfloat16* __restrict__ hp0)
{
    __shared__ float red[4];
    const int r = blockIdx.x;
    const int t = threadIdx.x;
    const size_t base = (size_t)r * DIM + t * 2;
    float z0 = attn_out[base], z1 = attn_out[base + 1];

    float s = z0 + z1;
    #pragma unroll
    for (int o = 32; o; o >>= 1) s += __shfl_xor(s, o);
    if ((t & 63) == 0) red[t >> 6] = s;
    __syncthreads();
    const float mean = (red[0] + red[1] + red[2] + red[3]) * (1.0f / DIM);
    __syncthreads();

    const float d0 = z0 - mean, d1 = z1 - mean;
    float vq = d0 * d0 + d1 * d1;
    #pragma unroll
    for (int o = 32; o; o >>= 1) vq += __shfl_xor(vq, o);
    if ((t & 63) == 0) red[t >> 6] = vq;
    __syncthreads();
    const float var = (red[0] + red[1] + red[2] + red[3]) * (1.0f / DIM);
    const float rstd = rsqrtf(var + 1e-5f);

    const float y0 = d0 * rstd + residual[base];
    const float y1 = d1 * rstd + residual[base + 1];
    __hip_bfloat16* out = hp0 + (size_t)(r + 1) * DIM + t * 2;
    out[0] = __float2bfloat16(y0);
    out[1] = __float2bfloat16(y1);
}

__global__ __launch_bounds__(256) void final_ln_kernel(
    const float* __restrict__ conv_out, const float* __restrict__ skip_out,
    float* __restrict__ out)
{
    __shared__ float red[4];
    const int r = blockIdx.x;
    const int t = threadIdx.x;
    const size_t base = (size_t)r * DIM + t * 2;
    float z0 = conv_out[base] + skip_out[base];
    float z1 = conv_out[base + 1] + skip_out[base + 1];

    float s = z0 + z1;
    #pragma unroll
    for (int o = 32; o; o >>= 1) s += __shfl_xor(s, o);
    if ((t & 63) == 0) red[t >> 6] = s;
    __syncthreads();
    const float mean = (red[0] + red[1] + red[2] + red[3]) * (1.0f / DIM);
    __syncthreads();

    const float d0 = z0 - mean, d1 = z1 - mean;
    float vq = d0 * d0 + d1 * d1;
    #pragma unroll
    for (int o = 32; o; o >>= 1) vq += __shfl_xor(vq, o);
    if ((t & 63) == 0) red[t >> 6] = vq;
    __syncthreads();
    const float var = (red[0] + red[1] + red[2] + red[3]) * (1.0f / DIM);
    const float rstd = rsqrtf(var + 1e-5f);

    out[base]     = d0 * rstd;
    out[base + 1] = d1 * rstd;
}

// ---------------------------------------------------------------------------
// One merged staging kernel (unchanged from R9)
// ---------------------------------------------------------------------------
#define SG0 (S_LEN * KDIM_P)
#define SG1 (5 * KDIM_P * DIM)
#define SG2 (DIM * DIM)
#define SG3 (KV_LD * KDIM_P)
#define SG4 (DIM * DIM)
#define SG5 (DIM * DIM)
#define SG6 (NLAYERS * DIM * CONV_K)
#define SG7 (S_PAD * KV_LD)
#define SG8 (4 * DIM)
#define SG9 (4096)
#define SG_TOTAL (SG0+SG1+SG2+SG3+SG4+SG5+SG6+SG7+SG8+SG9)

__global__ void stage_all_kernel(
    const float* __restrict__ x, const float* __restrict__ proj_w,
    const float* __restrict__ q_w, const float* __restrict__ k_w,
    const float* __restrict__ v_w, const float* __restrict__ out_w,
    const float* __restrict__ skip_w, const float* __restrict__ conv_w,
    __hip_bfloat16* src_b, __hip_bfloat16* projw_T, __hip_bfloat16* qw_b,
    __hip_bfloat16* W_all, __hip_bfloat16* outw_b, __hip_bfloat16* skipw_b,
    __hip_bfloat16* convwt, __hip_bfloat16* kv_b,
    __hip_bfloat16* hp0, __hip_bfloat16* hp1, float* zeros)
{
    int idx = blockIdx.x * 256 + threadIdx.x;
    if (idx >= SG_TOTAL) return;
    const __hip_bfloat16 zb = __float2bfloat16(0.f);

    if (idx < SG0) {
        int i = idx / KDIM_P, j = idx % KDIM_P;
        float v;
        if (j < 128)       v = x[i * 128 + j];
        else if (j < KDIM) { int e = j - 128; v = (float)(i & ((2 << e) - 1)) / (float)(1 << e); }
        else               v = 0.f;
        src_b[idx] = __float2bfloat16(v);
        return;
    }
    idx -= SG0;
    if (idx < SG1) {
        int j = idx / (KDIM_P * DIM);
        int rem = idx % (KDIM_P * DIM);
        int k = rem / DIM, d = rem % DIM;
        projw_T[idx] = (k < KDIM)
            ? __float2bfloat16(proj_w[(size_t)(j * DIM + d) * KDIM + k]) : zb;
        return;
    }
    idx -= SG1;
    if (idx < SG2) { qw_b[idx] = __float2bfloat16(q_w[idx]); return; }
    idx -= SG2;
    if (idx < SG3) {
        int r = idx / KDIM_P, c = idx % KDIM_P;
        float v = 0.f;
        if (c < KDIM) v = (r < DIM) ? k_w[(size_t)r * KDIM + c]
                                    : v_w[(size_t)(r - DIM) * KDIM + c];
        W_all[(size_t)(2560 + r) * KDIM_P + c] = __float2bfloat16(v);
        return;
    }
    idx -= SG3;
    if (idx < SG4) { outw_b[idx] = __float2bfloat16(out_w[idx]); return; }
    idx -= SG4;
    if (idx < SG5) { skipw_b[idx] = __float2bfloat16(skip_w[idx]); return; }
    idx -= SG5;
    if (idx < SG6) {
        int lc = idx / CONV_K;
        int rem = idx % CONV_K;
        int k = rem / DIM, ci = rem % DIM;
        convwt[idx] = __float2bfloat16(conv_w[(size_t)lc * CONV_K + ci * 3 + k]);
        return;
    }
    idx -= SG6;
    if (idx < SG7) { kv_b[(size_t)S_LEN * KV_LD + idx] = zb; return; }
    idx -= SG7;
    if (idx < SG8) {
        int t = idx % DIM, which = idx / DIM;
        if      (which == 0) hp0[t] = zb;
        else if (which == 1) hp0[(size_t)(L_LEN + 1) * DIM + t] = zb;
        else if (which == 2) hp1[t] = zb;
        else                 hp1[(size_t)(L_LEN + 1) * DIM + t] = zb;
        return;
    }
    idx -= SG8;
    zeros[idx] = 0.f;
}

// bias_all[n]: n<2560: qw[c,:] . proj_b[j,:] + in_b[c]; else in_b[512+...].
// One 64-lane wave per n (R9's serial version cost ~20 us).
__global__ void bias_all_kernel(const float* __restrict__ q_w,
                                const float* __restrict__ proj_b,
                                const float* __restrict__ in_b,
                                float* __restrict__ bias_all)
{
    const int n = blockIdx.x * 4 + (threadIdx.x >> 6);
    const int lane = threadIdx.x & 63;
    if (n >= NQKV) return;
    if (n < 2560) {
        const int j = n / DIM, c = n % DIM;
        float s = 0.f;
        #pragma unroll
        for (int it = 0; it < 8; ++it) {
            const int d = it * 64 + lane;
            s += q_w[(size_t)c * DIM + d] * proj_b[j * DIM + d];
        }
        #pragma unroll
        for (int o = 32; o; o >>= 1) s += __shfl_xor(s, o);
        if (lane == 0) bias_all[n] = s + in_b[c];
    } else {
        if (lane == 0) bias_all[n] = in_b[DIM + (n - 2560)];
    }
}

// ---------------------------------------------------------------------------
extern "C" void kernel_launch(void* const* d_in, const int* in_sizes, int n_in,
                              void* d_out, int out_size, void* d_ws, size_t ws_size,
                              hipStream_t stream)
{
    const float* x        = (const float*)d_in[0];
    const float* residual = (const float*)d_in[1];
    const float* proj_w   = (const float*)d_in[2];
    const float* proj_b   = (const float*)d_in[3];
    const float* q_w      = (const float*)d_in[4];
    const float* k_w      = (const float*)d_in[5];
    const float* v_w      = (const float*)d_in[6];
    const float* in_b     = (const float*)d_in[7];
    const float* out_w    = (const float*)d_in[8];
    const float* out_b    = (const float*)d_in[9];
    const float* conv_w   = (const float*)d_in[10];
    const float* conv_b   = (const float*)d_in[11];
    const float* skip_w   = (const float*)d_in[12];
    const float* skip_b   = (const float*)d_in[13];
    float* out = (float*)d_out;

    char* ws = (char*)d_ws;
    size_t off = 0;
    auto alloc = [&](size_t bytes) { char* p = ws + off; off += (bytes + 255) & ~(size_t)255; return p; };

    __hip_bfloat16* src_b   = (__hip_bfloat16*)alloc((size_t)S_LEN * KDIM_P * 2);
    __hip_bfloat16* projw_T = (__hip_bfloat16*)alloc((size_t)5 * KDIM_P * DIM * 2);
    __hip_bfloat16* qw_b    = (__hip_bfloat16*)alloc((size_t)DIM * DIM * 2);
    __hip_bfloat16* W_all   = (__hip_bfloat16*)alloc((size_t)NQKV * KDIM_P * 2);
    __hip_bfloat16* outw_b  = (__hip_bfloat16*)alloc((size_t)DIM * DIM * 2);
    __hip_bfloat16* skipw_b = (__hip_bfloat16*)alloc((size_t)DIM * DIM * 2);
    __hip_bfloat16* convwt  = (__hip_bfloat16*)alloc((size_t)NLAYERS * DIM * CONV_K * 2);
    float*          zeros   = (float*)alloc(4096 * 4);
    float*          bias_qkv= (float*)alloc(NQKV * 4);
    __hip_bfloat16* q_b     = (__hip_bfloat16*)alloc((size_t)L_LEN * DIM * 2);
    __hip_bfloat16* kv_b    = (__hip_bfloat16*)alloc((size_t)(S_LEN + S_PAD) * KV_LD * 2);
    __hip_bfloat16* o_b     = (__hip_bfloat16*)alloc((size_t)L_LEN * DIM * 2);
    float*          attn_f  = (float*)alloc((size_t)L_LEN * DIM * 4);
    __hip_bfloat16* hp0     = (__hip_bfloat16*)alloc((size_t)(L_LEN + 2) * DIM * 2);
    __hip_bfloat16* hp1     = (__hip_bfloat16*)alloc((size_t)(L_LEN + 2) * DIM * 2);
    float*          conv_f  = (float*)alloc((size_t)L_LEN * DIM * 4);
    float*          skip_f  = attn_f;
    (void)ws_size; (void)n_in; (void)in_sizes; (void)out_size;

    // --- staging (1 dispatch) + wave-parallel bias ---
    stage_all_kernel<<<(SG_TOTAL + 255) / 256, 256, 0, stream>>>(
        x, proj_w, q_w, k_w, v_w, out_w, skip_w, conv_w,
        src_b, projw_T, qw_b, W_all, outw_b, skipw_b, convwt, kv_b,
        hp0, hp1, zeros);
    bias_all_kernel<<<(NQKV + 3) / 4, 256, 0, stream>>>(
        q_w, proj_b, in_b, bias_qkv);

    // --- Wq5_j = qw @ projw_j : [512, KDIM_P] x5 -> W_all rows 0..2559 ---
    gemm_bk64<false, true, false><<<dim3(4, KDIM_P / 64, 5), 256, 0, stream>>>(
        qw_b, DIM, projw_T, DIM, zeros, W_all, nullptr, KDIM_P, DIM,
        0, (long)KDIM_P * DIM, (long)DIM * KDIM_P, nullptr, nullptr);

    // --- fused QKV: src [2048,192] x W_all [3584,192]^T, reshape epilogue ---
    gemm_bk64<false, true, true><<<dim3(S_LEN / 128, NQKV / 64), 256, 0, stream>>>(
        src_b, KDIM_P, W_all, KDIM_P, bias_qkv, nullptr, nullptr, 0, KDIM_P,
        0, 0, 0, q_b, kv_b);

    // --- banded MFMA attention ---
    attn_mfma_kernel<<<L_LEN / 16, 256, 0, stream>>>(q_b, kv_b, kv_b + DIM, o_b);

    // --- out proj -> f32 ---
    gemm_bk64<false, false, false><<<dim3(L_LEN / 128, DIM / 64), 256, 0, stream>>>(
        o_b, DIM, outw_b, DIM, out_b, nullptr, attn_f, DIM, DIM,
        0, 0, 0, nullptr, nullptr);

    // --- LN + residual -> hp0 rows 1..L (bf16) ---
    ln_residual_kernel<<<L_LEN, 256, 0, stream>>>(attn_f, residual, hp0);

    // --- skip GEMM ---
    gemm_bk64<false, false, false><<<dim3(L_LEN / 128, DIM / 64), 256, 0, stream>>>(
        hp0 + DIM, DIM, skipw_b, DIM, skip_b, nullptr, skip_f, DIM, DIM,
        0, 0, 0, nullptr, nullptr);

    // --- conv stack: sliding-window GEMMs, K=1536 ---
    gemm_bk64<true, true, false><<<dim3(L_LEN / 128, DIM / 64), 256, 0, stream>>>(
        hp0, DIM, convwt, CONV_K, conv_b, hp1 + DIM, nullptr, DIM, CONV_K,
        0, 0, 0, nullptr, nullptr);
    gemm_bk64<true, true, false><<<dim3(L_LEN / 128, DIM / 64), 256, 0, stream>>>(
        hp1, DIM, convwt + (size_t)DIM * CONV_K, CONV_K, conv_b + DIM, hp0 + DIM, nullptr, DIM, CONV_K,
        0, 0, 0, nullptr, nullptr);
    gemm_bk64<true, false, false><<<dim3(L_LEN / 128, DIM / 64), 256, 0, stream>>>(
        hp0, DIM, convwt + (size_t)2 * DIM * CONV_K, CONV_K, conv_b + 2 * DIM, nullptr, conv_f, DIM, CONV_K,
        0, 0, 0, nullptr, nullptr);

    // --- final LN ---
    final_ln_kernel<<<L_LEN, 256, 0, stream>>>(conv_f, skip_f, out);
}